// Round 3
// baseline (511.628 us; speedup 1.0000x reference)
//
#include <hip/hip_runtime.h>
#include <hip/hip_bf16.h>
#include <stdint.h>

typedef unsigned short u16;
typedef unsigned int u32;
typedef __bf16 bf16x8 __attribute__((ext_vector_type(8)));
typedef float f32x4 __attribute__((ext_vector_type(4)));
typedef u16 u16x8 __attribute__((ext_vector_type(8)));

#define S_LEN 2048
#define DMODEL 4096
#define NHEADS 32
#define NKVH 8
#define DHEAD 128
#define LDQK 6144   // row stride of fused QKV activation buffer

__device__ __forceinline__ float bf2f(u16 x) {
    union { u32 i; float f; } u; u.i = ((u32)x) << 16; return u.f;
}
__device__ __forceinline__ u16 f2bf(float f) {
    union { float f; u32 i; } u; u.f = f;
    u32 x = u.i;
    return (u16)((x + 0x7fffu + ((x >> 16) & 1u)) >> 16);
}
__device__ __forceinline__ bf16x8 ld_bf8(const void* p) {
    int4 v = *(const int4*)p;
    return __builtin_bit_cast(bf16x8, v);
}

// ---------------- fp32 -> bf16 elementwise ----------------
__global__ void k_cvt(const float* __restrict__ in, u16* __restrict__ out, int n8) {
    int i = blockIdx.x * 256 + threadIdx.x;
    if (i >= n8) return;
    const float4* p = (const float4*)in + (size_t)i * 2;
    float4 a = p[0], b = p[1];
    u16x8 o;
    o[0]=f2bf(a.x); o[1]=f2bf(a.y); o[2]=f2bf(a.z); o[3]=f2bf(a.w);
    o[4]=f2bf(b.x); o[5]=f2bf(b.y); o[6]=f2bf(b.z); o[7]=f2bf(b.w);
    *((u16x8*)out + i) = o;
}

// ---------------- transpose (+convert) to bf16: in[R][C] (ldin) -> out[C][R] ----------------
template<typename TIN>
__global__ void k_transpose_bf16(const TIN* __restrict__ in, u16* __restrict__ out,
                                 int R, int C, int ldin) {
    __shared__ u16 tile[32][33];
    int c0 = blockIdx.x * 32, r0 = blockIdx.y * 32;
    int tx = threadIdx.x & 31, ty = threadIdx.x >> 5;
    #pragma unroll
    for (int i = 0; i < 4; i++) {
        int r = ty + i * 8;
        TIN v = in[(size_t)(r0 + r) * ldin + c0 + tx];
        if constexpr (sizeof(TIN) == 4) tile[r][tx] = f2bf((float)v);
        else tile[r][tx] = (u16)v;
    }
    __syncthreads();
    #pragma unroll
    for (int i = 0; i < 4; i++) {
        int r = ty + i * 8;
        out[(size_t)(c0 + r) * R + r0 + tx] = tile[tx][r];
    }
}

// ---------------- RoPE in place on [S][nh*128] bf16 (row stride ld) ----------------
__global__ void k_rope(u16* __restrict__ X, const float* __restrict__ cosT,
                       const float* __restrict__ sinT, int nh, int ld) {
    int idx = blockIdx.x * 256 + threadIdx.x;
    int d = idx & 63;
    int h = (idx >> 6) % nh;
    int s = idx / (64 * nh);
    u16* p = X + (size_t)s * ld + h * DHEAD;
    float x1 = bf2f(p[d]), x2 = bf2f(p[d + 64]);
    float c1 = cosT[s * DHEAD + d],      s1 = sinT[s * DHEAD + d];
    float c2 = cosT[s * DHEAD + d + 64], s2 = sinT[s * DHEAD + d + 64];
    p[d]      = f2bf(x1 * c1 - x2 * s1);
    p[d + 64] = f2bf(x2 * c2 + x1 * s2);
}

typedef const __attribute__((address_space(1))) u32 GBUF;
typedef __attribute__((address_space(3))) u32 LBUF;

// ---------------- 256x256 8-phase GEMM (T2 swizzle + T3/T4 counted vmcnt + T5) ----
// C = A[M][K] x Bt[N][K]^T over K-slice [kz*k_len, (kz+1)*k_len), kz from grid.
// kz==0 -> C0, kz==1 -> C1. 512 threads = 8 waves (2M x 4N); per-wave 128x64 out.
// LDS 128KB: A[buf][half][128][64]u16 @0, B same @65536. st_16x32 XOR swizzle
// (byte ^= ((byte>>9)&1)<<5) applied on ds_read and inverse-applied on the
// global SOURCE of global_load_lds (linear LDS dest) — rule 21.
template<typename OUT_T>
__global__ __launch_bounds__(512, 2)
void k_gemm256(const u16* __restrict__ A, const u16* __restrict__ Bt,
               OUT_T* __restrict__ C0, OUT_T* __restrict__ C1,
               int M, int N, int K, int mtiles, int ntiles, int k_len) {
    extern __shared__ __align__(16) char smem[];

    const int nwg = gridDim.x;
    const int cpx = nwg >> 3;                       // nwg % 8 == 0 by launch
    const int flat = blockIdx.x;
    const int swz = (flat & 7) * cpx + (flat >> 3); // XCD-aware swizzle (T1)
    const int tile = swz % (mtiles * ntiles);
    const int kz = swz / (mtiles * ntiles);
    const int bm = (tile / ntiles) * 256, bn = (tile % ntiles) * 256;
    const int k0b = kz * k_len;
    OUT_T* __restrict__ Cz = kz ? C1 : C0;

    const int tid = threadIdx.x, lane = tid & 63, wid = tid >> 6;
    const int wr = wid >> 2, wc = wid & 3;
    const int g = lane >> 4, lr = lane & 15;
    const u32 lrsw = ((lr >> 2) & 1) << 5;          // read-side swizzle bit

    // staging chunk precompute (2 chunks/thread/half-tile)
    const u16* srcA[2]; const u16* srcB[2]; u32 ldsl[2];
    #pragma unroll
    for (int j = 0; j < 2; j++) {
        int c = j * 512 + tid;                       // 0..1023
        int rowc = c >> 3;
        int colsw = (c & 7) ^ (((c >> 5) & 1) << 1); // inverse-swizzled source col (16B units)
        srcA[j] = A  + (size_t)(bm + rowc) * K + k0b + colsw * 8;
        srcB[j] = Bt + (size_t)(bn + rowc) * K + k0b + colsw * 8;
        ldsl[j] = (u32)(j * 512 + wid * 64) * 16;    // linear LDS dest (uniform per wave)
    }

    auto stageHT = [&](int buf, int kind, int half, int kt) {
        #pragma unroll
        for (int j = 0; j < 2; j++) {
            const u16* src = (kind ? srcB[j] : srcA[j]) + (size_t)half * 128 * K + kt * 64;
            u32 off = (u32)kind * 65536 + (u32)buf * 32768 + (u32)half * 16384 + ldsl[j];
            __builtin_amdgcn_global_load_lds((GBUF*)src, (LBUF*)(smem + off), 16, 0, 0);
        }
    };

    f32x4 acc[8][4] = {};
    bf16x8 af[4][2], bfr[2][2];

    const int NT = k_len >> 6;                       // 64-wide K-tiles, NT even

    // prologue: buf0 <- kt0 (4 HTs), buf1.HT0 <- kt1
    stageHT(0, 0, 0, 0); stageHT(0, 0, 1, 0); stageHT(0, 1, 0, 0); stageHT(0, 1, 1, 0);
    stageHT(1, 0, 0, 1);
    __builtin_amdgcn_sched_barrier(0);
    asm volatile("s_waitcnt vmcnt(2)" ::: "memory");
    __builtin_amdgcn_sched_barrier(0);
    __builtin_amdgcn_s_barrier();

    // stage maps: phase -> {buf, HT(kind,half), kt-selector}
    // p0-2: buf1 HT1..3 @ kt(2t+1); p3-6: buf0 HT0..3 @ kt(2t+2); p7: buf1 HT0 @ kt(2t+3)
    const int stg_buf[8] = {1,1,1, 0,0,0,0, 1};
    const int stg_ht [8] = {1,2,3, 0,1,2,3, 0};

    for (int t = 0; t < (NT >> 1); t++) {
        const int kt1 = 2 * t + 1;
        int kt2 = 2 * t + 2; if (kt2 >= NT) kt2 -= NT;   // wrapped prefetch keeps
        int kt3 = 2 * t + 3; if (kt3 >= NT) kt3 -= NT;   // vmcnt arithmetic exact
        #pragma unroll
        for (int p = 0; p < 8; p++) {
            const int q = p & 3, bs = p >> 2;
            const int mh = q & 1, nh = q >> 1;
            // ---- GAP: prefetch stage (except p3/p7) + ds_reads ----
            if (p != 3 && p != 7) {
                int kts = (p < 3) ? kt1 : kt2;
                stageHT(stg_buf[p], stg_ht[p] >> 1, stg_ht[p] & 1, kts);
            }
            if ((q & 1) == 0) {   // nh changed or new buffer: reload B pair
                #pragma unroll
                for (int n2 = 0; n2 < 2; n2++)
                    #pragma unroll
                    for (int kk = 0; kk < 2; kk++)
                        bfr[n2][kk] = ld_bf8(smem + 65536 + bs * 32768 + (wc >> 1) * 16384 +
                            ((u32)(((wc & 1) * 64 + (nh * 2 + n2) * 16 + lr) * 128 + kk * 64 + g * 16) ^ lrsw));
            }
            #pragma unroll
            for (int m4 = 0; m4 < 4; m4++)
                #pragma unroll
                for (int kk = 0; kk < 2; kk++)
                    af[m4][kk] = ld_bf8(smem + bs * 32768 + wr * 16384 +
                        ((u32)(((mh * 4 + m4) * 16 + lr) * 128 + kk * 64 + g * 16) ^ lrsw));
            __builtin_amdgcn_sched_barrier(0);
            __builtin_amdgcn_s_barrier();
            asm volatile("s_waitcnt lgkmcnt(0)" ::: "memory");
            __builtin_amdgcn_sched_barrier(0);
            __builtin_amdgcn_s_setprio(1);
            #pragma unroll
            for (int m4 = 0; m4 < 4; m4++)
                #pragma unroll
                for (int n2 = 0; n2 < 2; n2++)
                    #pragma unroll
                    for (int kk = 0; kk < 2; kk++)
                        acc[mh * 4 + m4][nh * 2 + n2] = __builtin_amdgcn_mfma_f32_16x16x32_bf16(
                            af[m4][kk], bfr[n2][kk], acc[mh * 4 + m4][nh * 2 + n2], 0, 0, 0);
            __builtin_amdgcn_s_setprio(0);
            if (p == 3 || p == 7) {   // stage into just-released buffer + counted wait
                int kts = (p == 3) ? kt2 : kt3;
                stageHT(stg_buf[p], stg_ht[p] >> 1, stg_ht[p] & 1, kts);
                __builtin_amdgcn_sched_barrier(0);
                asm volatile("s_waitcnt vmcnt(2)" ::: "memory");
                __builtin_amdgcn_sched_barrier(0);
            }
            __builtin_amdgcn_s_barrier();
        }
    }

    #pragma unroll
    for (int m = 0; m < 8; m++)
        #pragma unroll
        for (int n = 0; n < 4; n++)
            #pragma unroll
            for (int r = 0; r < 4; r++) {
                int row = bm + wr * 128 + m * 16 + g * 4 + r;
                int col = bn + wc * 64 + n * 16 + lr;
                float v = acc[m][n][r];
                if constexpr (sizeof(OUT_T) == 2) Cz[(size_t)row * N + col] = f2bf(v);
                else                              Cz[(size_t)row * N + col] = v;
            }
}

// ---------------- split-K combine: out += p0 (fp32) ----------------
__global__ void k_addp(const float* __restrict__ p0, float* __restrict__ out, int n8) {
    int i = blockIdx.x * 256 + threadIdx.x;
    if (i >= n8) return;
    const float4* a = (const float4*)p0 + (size_t)i * 2;
    float4* o = (float4*)out + (size_t)i * 2;
    float4 a0 = a[0], a1 = a[1], o0 = o[0], o1 = o[1];
    o0.x += a0.x; o0.y += a0.y; o0.z += a0.z; o0.w += a0.w;
    o1.x += a1.x; o1.y += a1.y; o1.z += a1.z; o1.w += a1.w;
    o[0] = o0; o[1] = o1;
}

// ---------------- causal GQA flash attention, 2-phase pipelined ----------------
__global__ __launch_bounds__(256)
void k_attn2(const u16* __restrict__ Qb, const u16* __restrict__ Kb,
             const u16* __restrict__ VbT, u16* __restrict__ Ab) {
    extern __shared__ __align__(16) char smem[];

    const int p = blockIdx.x, h = blockIdx.y, hk = h >> 2;
    const int tid = threadIdx.x, lane = tid & 63, wid = tid >> 6;
    const int g = lane >> 4, lr = lane & 15;
    const float scale = 0.08838834764831845f;  // 1/sqrt(128)
    const int qtA = p, qtB = 31 - p, nA = qtA + 1;
    const int NIT = 33;

    const int krow_l = lane >> 4, kc16 = lane & 15;
    const int vrow_l = lane >> 3, vc8  = lane & 7;

    u16* PsB = (u16*)(smem + 65536) + wid * 16 * 72;

    auto stage = [&](int buf, int k0) {
        u16* KsD = (u16*)smem + buf * 8192;
        u16* VtD = (u16*)(smem + 32768) + buf * 8192;
        #pragma unroll
        for (int j = 0; j < 4; j++) {
            int rowt = wid * 16 + j * 4 + krow_l;
            int c16  = kc16 ^ (rowt & 7);
            __builtin_amdgcn_global_load_lds(
                (GBUF*)(Kb + (size_t)(k0 + rowt) * LDQK + hk * DHEAD + c16 * 8),
                (LBUF*)(KsD + (wid * 16 + j * 4) * 128), 16, 0, 0);
        }
        #pragma unroll
        for (int j = 0; j < 4; j++) {
            int rowt = wid * 32 + j * 8 + vrow_l;
            int c8   = vc8 ^ (rowt & 7);
            __builtin_amdgcn_global_load_lds(
                (GBUF*)(VbT + (size_t)(hk * DHEAD + rowt) * S_LEN + k0 + c8 * 8),
                (LBUF*)(VtD + (wid * 32 + j * 8) * 64), 16, 0, 0);
        }
    };

    bf16x8 qf[4];
    f32x4 acc[8];
    float m[4], lsum[4];
    int qt = qtA, q0 = qtA * 64;

    stage(0, 0);
    asm volatile("s_waitcnt vmcnt(0)" ::: "memory");
    __builtin_amdgcn_s_barrier();

    for (int i = 0; i < NIT; i++) {
        const int kt = (i < nA) ? i : (i - nA);
        if (i + 1 < NIT) {
            int kt1 = (i + 1 < nA) ? (i + 1) : (i + 1 - nA);
            stage((i + 1) & 1, kt1 * 64);
        }
        if (i == 0 || i == nA) {
            if (i == nA) {
                #pragma unroll
                for (int n = 0; n < 8; n++)
                    #pragma unroll
                    for (int r = 0; r < 4; r++)
                        Ab[(size_t)(q0 + wid * 16 + g * 4 + r) * DMODEL + h * DHEAD + n * 16 + lr]
                            = f2bf(acc[n][r] / lsum[r]);
            }
            qt = (i == 0) ? qtA : qtB;
            q0 = qt * 64;
            const u16* qrow = Qb + (size_t)(q0 + wid * 16 + lr) * LDQK + h * DHEAD;
            #pragma unroll
            for (int c = 0; c < 4; c++) qf[c] = ld_bf8(qrow + c * 32 + g * 8);
            #pragma unroll
            for (int n = 0; n < 8; n++) acc[n] = (f32x4){0.f, 0.f, 0.f, 0.f};
            #pragma unroll
            for (int r = 0; r < 4; r++) { m[r] = -1e30f; lsum[r] = 0.f; }
        }

        const char* KsB = smem + (i & 1) * 16384;
        const char* VtB = smem + 32768 + (i & 1) * 16384;

        f32x4 sf[4];
        __builtin_amdgcn_s_setprio(1);
        #pragma unroll
        for (int st = 0; st < 4; st++) {
            f32x4 s = {0.f, 0.f, 0.f, 0.f};
            #pragma unroll
            for (int c = 0; c < 4; c++) {
                int row = st * 16 + lr;
                int cb = (c * 32 + g * 8) * 2;
                bf16x8 kf = ld_bf8(KsB + row * 256 + (cb ^ ((row & 7) << 4)));
                s = __builtin_amdgcn_mfma_f32_16x16x32_bf16(qf[c], kf, s, 0, 0, 0);
            }
            sf[st] = s;
        }
        __builtin_amdgcn_s_setprio(0);

        if (kt == qt) {
            #pragma unroll
            for (int st = 0; st < 4; st++)
                #pragma unroll
                for (int r = 0; r < 4; r++) {
                    int qg = wid * 16 + g * 4 + r;
                    int kg = st * 16 + lr;
                    sf[st][r] = (kg > qg) ? -1e30f : sf[st][r] * scale;
                }
        } else {
            #pragma unroll
            for (int st = 0; st < 4; st++)
                #pragma unroll
                for (int r = 0; r < 4; r++) sf[st][r] *= scale;
        }

        float corr[4];
        #pragma unroll
        for (int r = 0; r < 4; r++) {
            float v = fmaxf(fmaxf(sf[0][r], sf[1][r]), fmaxf(sf[2][r], sf[3][r]));
            #pragma unroll
            for (int off = 1; off < 16; off <<= 1) v = fmaxf(v, __shfl_xor(v, off, 64));
            float mn = fmaxf(m[r], v);
            corr[r] = __expf(m[r] - mn);
            m[r] = mn;
        }
        float ts[4] = {0.f, 0.f, 0.f, 0.f};
        #pragma unroll
        for (int st = 0; st < 4; st++)
            #pragma unroll
            for (int r = 0; r < 4; r++) {
                float pv = __expf(sf[st][r] - m[r]);
                sf[st][r] = pv;
                ts[r] += pv;
            }
        #pragma unroll
        for (int r = 0; r < 4; r++) {
            #pragma unroll
            for (int off = 1; off < 16; off <<= 1) ts[r] += __shfl_xor(ts[r], off, 64);
            lsum[r] = lsum[r] * corr[r] + ts[r];
        }
        #pragma unroll
        for (int n = 0; n < 8; n++)
            #pragma unroll
            for (int r = 0; r < 4; r++) acc[n][r] *= corr[r];

        #pragma unroll
        for (int st = 0; st < 4; st++)
            #pragma unroll
            for (int r = 0; r < 4; r++)
                PsB[(g * 4 + r) * 72 + st * 16 + lr] = f2bf(sf[st][r]);
        asm volatile("s_waitcnt lgkmcnt(0)" ::: "memory");

        __builtin_amdgcn_s_setprio(1);
        #pragma unroll
        for (int c2 = 0; c2 < 2; c2++) {
            bf16x8 pa = ld_bf8(PsB + lr * 72 + c2 * 32 + g * 8);
            #pragma unroll
            for (int n = 0; n < 8; n++) {
                int row = n * 16 + lr;
                int cb = (c2 * 32 + g * 8) * 2;
                bf16x8 vf = ld_bf8(VtB + row * 128 + (cb ^ ((row & 7) << 4)));
                acc[n] = __builtin_amdgcn_mfma_f32_16x16x32_bf16(pa, vf, acc[n], 0, 0, 0);
            }
        }
        __builtin_amdgcn_s_setprio(0);

        asm volatile("s_waitcnt lgkmcnt(0)" ::: "memory");
        __builtin_amdgcn_sched_barrier(0);
        asm volatile("s_waitcnt vmcnt(0)" ::: "memory");
        __builtin_amdgcn_s_barrier();
    }

    #pragma unroll
    for (int n = 0; n < 8; n++)
        #pragma unroll
        for (int r = 0; r < 4; r++)
            Ab[(size_t)(q0 + wid * 16 + g * 4 + r) * DMODEL + h * DHEAD + n * 16 + lr]
                = f2bf(acc[n][r] / lsum[r]);
}

extern "C" void kernel_launch(void* const* d_in, const int* in_sizes, int n_in,
                              void* d_out, int out_size, void* d_ws, size_t ws_size,
                              hipStream_t stream) {
    const float* hidden = (const float*)d_in[0];
    const float* cosT   = (const float*)d_in[1];
    const float* sinT   = (const float*)d_in[2];
    // d_in[3] attention_mask: known causal, implemented directly
    const float* Wq = (const float*)d_in[4];
    const float* Wk = (const float*)d_in[5];
    const float* Wv = (const float*)d_in[6];
    const float* Wo = (const float*)d_in[7];
    float* out = (float*)d_out;
    char* ws = (char*)d_ws;

    // workspace (peak 120 MB):
    //   [0,16)    Xbf [2048][4096] bf16; later reused as Ab
    //   [16,64)   WqkvT [6144][4096] bf16 (dead after QKV GEMM);
    //             then VbT @[16,20); then split-K partial0 (f32, 32MB) @[20,52)
    //   [64,96)   WoT [4096][4096] bf16
    //   [96,120)  QKVb [2048][6144] bf16
    u16*   Xbf   = (u16*)ws;
    u16*   WqkvT = (u16*)(ws + (16u << 20));
    u16*   VbT   = (u16*)(ws + (16u << 20));        // alias: valid after QKV GEMM
    float* P0    = (float*)(ws + (20u << 20));      // alias: valid after attention
    u16*   WoT   = (u16*)(ws + (64u << 20));
    u16*   QKVb  = (u16*)(ws + (96u << 20));
    u16*   Ab    = Xbf;

    k_cvt<<<dim3((S_LEN * DMODEL / 8) / 256), 256, 0, stream>>>(hidden, Xbf, S_LEN * DMODEL / 8);
    k_transpose_bf16<float><<<dim3(4096 / 32, 4096 / 32), 256, 0, stream>>>(Wq, WqkvT, 4096, 4096, 4096);
    k_transpose_bf16<float><<<dim3(1024 / 32, 4096 / 32), 256, 0, stream>>>(Wk, WqkvT + (size_t)4096 * 4096, 4096, 1024, 1024);
    k_transpose_bf16<float><<<dim3(1024 / 32, 4096 / 32), 256, 0, stream>>>(Wv, WqkvT + (size_t)5120 * 4096, 4096, 1024, 1024);
    k_transpose_bf16<float><<<dim3(4096 / 32, 4096 / 32), 256, 0, stream>>>(Wo, WoT, 4096, 4096, 4096);

    hipFuncSetAttribute((const void*)k_gemm256<u16>,  hipFuncAttributeMaxDynamicSharedMemorySize, 131072);
    hipFuncSetAttribute((const void*)k_gemm256<float>, hipFuncAttributeMaxDynamicSharedMemorySize, 131072);

    // fused QKV projection: [2048][4096] x [6144][4096]^T -> [2048][6144]; 192 wgs
    k_gemm256<u16><<<192, 512, 131072, stream>>>(Xbf, WqkvT, QKVb, QKVb, 2048, 6144, 4096, 8, 24, 4096);

    // RoPE on Q (cols 0..4095) and K (cols 4096..5119)
    k_rope<<<(2048 * 32 * 64) / 256, 256, 0, stream>>>(QKVb, cosT, sinT, 32, LDQK);
    k_rope<<<(2048 * 8 * 64) / 256, 256, 0, stream>>>(QKVb + 4096, cosT, sinT, 8, LDQK);

    // V^T (cols 5120..6143 of QKVb) -> VbT [1024][2048]
    k_transpose_bf16<u16><<<dim3(1024 / 32, 2048 / 32), 256, 0, stream>>>(QKVb + 5120, VbT, 2048, 1024, LDQK);

    // attention: 16 q-tile pairs x 32 heads, 74752 B dynamic LDS
    hipFuncSetAttribute((const void*)k_attn2, hipFuncAttributeMaxDynamicSharedMemorySize, 74752);
    k_attn2<<<dim3(16, 32), 256, 74752, stream>>>(QKVb, QKVb + 4096, VbT, Ab);

    // output projection, split-K=2: kz=0 -> P0 (ws), kz=1 -> out; then out += P0
    k_gemm256<float><<<256, 512, 131072, stream>>>(Ab, WoT, P0, out, 2048, 4096, 4096, 8, 16, 2048);
    k_addp<<<(2048 * 4096 / 8) / 256, 256, 0, stream>>>(P0, out, 2048 * 4096 / 8);
}

// Round 4
// 463.429 us; speedup vs baseline: 1.1040x; 1.1040x over previous
//
#include <hip/hip_runtime.h>
#include <hip/hip_bf16.h>
#include <stdint.h>

typedef unsigned short u16;
typedef unsigned int u32;
typedef __bf16 bf16x8 __attribute__((ext_vector_type(8)));
typedef float f32x4 __attribute__((ext_vector_type(4)));
typedef u16 u16x8 __attribute__((ext_vector_type(8)));

#define S_LEN 2048
#define DMODEL 4096
#define NHEADS 32
#define NKVH 8
#define DHEAD 128
#define LDQK 6144   // row stride of fused QKV activation buffer

__device__ __forceinline__ float bf2f(u16 x) {
    union { u32 i; float f; } u; u.i = ((u32)x) << 16; return u.f;
}
__device__ __forceinline__ u16 f2bf(float f) {
    union { float f; u32 i; } u; u.f = f;
    u32 x = u.i;
    return (u16)((x + 0x7fffu + ((x >> 16) & 1u)) >> 16);
}
__device__ __forceinline__ bf16x8 ld_bf8(const void* p) {
    int4 v = *(const int4*)p;
    return __builtin_bit_cast(bf16x8, v);
}

// ---------------- fp32 -> bf16 elementwise ----------------
__global__ void k_cvt(const float* __restrict__ in, u16* __restrict__ out, int n8) {
    int i = blockIdx.x * 256 + threadIdx.x;
    if (i >= n8) return;
    const float4* p = (const float4*)in + (size_t)i * 2;
    float4 a = p[0], b = p[1];
    u16x8 o;
    o[0]=f2bf(a.x); o[1]=f2bf(a.y); o[2]=f2bf(a.z); o[3]=f2bf(a.w);
    o[4]=f2bf(b.x); o[5]=f2bf(b.y); o[6]=f2bf(b.z); o[7]=f2bf(b.w);
    *((u16x8*)out + i) = o;
}

// ---------------- transpose (+convert) to bf16: in[R][C] (ldin) -> out[C][R] ----------------
template<typename TIN>
__global__ void k_transpose_bf16(const TIN* __restrict__ in, u16* __restrict__ out,
                                 int R, int C, int ldin) {
    __shared__ u16 tile[32][33];
    int c0 = blockIdx.x * 32, r0 = blockIdx.y * 32;
    int tx = threadIdx.x & 31, ty = threadIdx.x >> 5;
    #pragma unroll
    for (int i = 0; i < 4; i++) {
        int r = ty + i * 8;
        TIN v = in[(size_t)(r0 + r) * ldin + c0 + tx];
        if constexpr (sizeof(TIN) == 4) tile[r][tx] = f2bf((float)v);
        else tile[r][tx] = (u16)v;
    }
    __syncthreads();
    #pragma unroll
    for (int i = 0; i < 4; i++) {
        int r = ty + i * 8;
        out[(size_t)(c0 + r) * R + r0 + tx] = tile[tx][r];
    }
}

// ---------------- RoPE in place on [S][nh*128] bf16 (row stride ld) ----------------
__global__ void k_rope(u16* __restrict__ X, const float* __restrict__ cosT,
                       const float* __restrict__ sinT, int nh, int ld) {
    int idx = blockIdx.x * 256 + threadIdx.x;
    int d = idx & 63;
    int h = (idx >> 6) % nh;
    int s = idx / (64 * nh);
    u16* p = X + (size_t)s * ld + h * DHEAD;
    float x1 = bf2f(p[d]), x2 = bf2f(p[d + 64]);
    float c1 = cosT[s * DHEAD + d],      s1 = sinT[s * DHEAD + d];
    float c2 = cosT[s * DHEAD + d + 64], s2 = sinT[s * DHEAD + d + 64];
    p[d]      = f2bf(x1 * c1 - x2 * s1);
    p[d + 64] = f2bf(x2 * c2 + x1 * s2);
}

typedef const __attribute__((address_space(1))) u32 GBUF;
typedef __attribute__((address_space(3))) u32 LBUF;

// ---------------- 256x256 8-phase GEMM ----------------
// C = A[M][K] x Bt[N][K]^T over K-slice [kz*k_len, (kz+1)*k_len).
// kz==0 -> C0, kz==1 -> C1. 512 threads = 8 waves (2M x 4N); per-wave 128x64 out.
// LDS 128KB: A[buf][half][128][64]u16 @0, B same @65536.
// 3-bit XOR swizzle: 16B-chunk col ^= (row&7) — uniform 8 lanes/bank-quad on
// ds_read_b128 (conflict-free floor); inverse applied on global SOURCE of
// global_load_lds, LDS dest stays linear (rule 21).
// Phase order (mh,nh) = (0,0),(0,1),(1,0),(1,1); bfr[2] retained in regs so
// each LDS byte is ds_read exactly once per K-tile (24KB/wave/K-tile).
template<typename OUT_T>
__global__ __launch_bounds__(512, 2)
void k_gemm256(const u16* __restrict__ A, const u16* __restrict__ Bt,
               OUT_T* __restrict__ C0, OUT_T* __restrict__ C1,
               int M, int N, int K, int mtiles, int ntiles, int k_len) {
    extern __shared__ __align__(16) char smem[];

    const int nwg = gridDim.x;
    const int cpx = nwg >> 3;                       // nwg % 8 == 0 by launch
    const int flat = blockIdx.x;
    const int swz = (flat & 7) * cpx + (flat >> 3); // XCD-aware swizzle (T1)
    const int tile = swz % (mtiles * ntiles);
    const int kz = swz / (mtiles * ntiles);
    const int bm = (tile / ntiles) * 256, bn = (tile % ntiles) * 256;
    const int k0b = kz * k_len;
    OUT_T* __restrict__ Cz = kz ? C1 : C0;

    const int tid = threadIdx.x, lane = tid & 63, wid = tid >> 6;
    const int wr = wid >> 2, wc = wid & 3;
    const int g = lane >> 4, lr = lane & 15;

    // staging chunk precompute (2 chunks/thread/half-tile), 3-bit inverse swizzle on source
    const u16* srcA[2]; const u16* srcB[2]; u32 ldsl[2];
    #pragma unroll
    for (int j = 0; j < 2; j++) {
        int c = j * 512 + tid;                       // 0..1023
        int rowc = c >> 3;
        int colsw = (c & 7) ^ (rowc & 7);            // inverse-swizzled source col (16B units)
        srcA[j] = A  + (size_t)(bm + rowc) * K + k0b + colsw * 8;
        srcB[j] = Bt + (size_t)(bn + rowc) * K + k0b + colsw * 8;
        ldsl[j] = (u32)(j * 512 + wid * 64) * 16;    // linear LDS dest (uniform per wave)
    }

    auto stageHT = [&](int buf, int kind, int half, int kt) {
        #pragma unroll
        for (int j = 0; j < 2; j++) {
            const u16* src = (kind ? srcB[j] : srcA[j]) + (size_t)half * 128 * K + kt * 64;
            u32 off = (u32)kind * 65536 + (u32)buf * 32768 + (u32)half * 16384 + ldsl[j];
            __builtin_amdgcn_global_load_lds((GBUF*)src, (LBUF*)(smem + off), 16, 0, 0);
        }
    };

    // swizzled ds_read byte offset within a [128][64]u16 half-tile
    auto rdoff = [&](int row, int kk) -> u32 {
        return (u32)(row * 128 + ((((kk << 2) + g) ^ (row & 7)) << 4));
    };

    f32x4 acc[8][4] = {};
    bf16x8 af[4][2], bfr[2][2][2];

    const int NT = k_len >> 6;                       // 64-wide K-tiles, NT even

    // prologue: buf0 <- kt0 (4 HTs), buf1.HT0 <- kt1
    stageHT(0, 0, 0, 0); stageHT(0, 0, 1, 0); stageHT(0, 1, 0, 0); stageHT(0, 1, 1, 0);
    stageHT(1, 0, 0, 1);
    __builtin_amdgcn_sched_barrier(0);
    asm volatile("s_waitcnt vmcnt(2)" ::: "memory");
    __builtin_amdgcn_sched_barrier(0);
    __builtin_amdgcn_s_barrier();

    // stage maps: p0-2: buf1 HT1..3 @ kt1; p3-6: buf0 HT0..3 @ kt2; p7: buf1 HT0 @ kt3
    const int stg_buf[8] = {1,1,1, 0,0,0,0, 1};
    const int stg_ht [8] = {1,2,3, 0,1,2,3, 0};

    for (int t = 0; t < (NT >> 1); t++) {
        const int kt1 = 2 * t + 1;
        int kt2 = 2 * t + 2; if (kt2 >= NT) kt2 -= NT;   // wrapped prefetch keeps
        int kt3 = 2 * t + 3; if (kt3 >= NT) kt3 -= NT;   // vmcnt arithmetic exact
        #pragma unroll
        for (int p = 0; p < 8; p++) {
            const int q = p & 3, bs = p >> 2;
            const int mh = q >> 1, nh = q & 1;
            // ---- GAP: prefetch stage (except p3/p7) + ds_reads ----
            if (p != 3 && p != 7) {
                int kts = (p < 3) ? kt1 : kt2;
                stageHT(stg_buf[p], stg_ht[p] >> 1, stg_ht[p] & 1, kts);
            }
            if (q == 0 || q == 2) {   // new mh: load A fragments (8 reads)
                #pragma unroll
                for (int m4 = 0; m4 < 4; m4++)
                    #pragma unroll
                    for (int kk = 0; kk < 2; kk++)
                        af[m4][kk] = ld_bf8(smem + bs * 32768 + wr * 16384 +
                                            rdoff((mh * 4 + m4) * 16 + lr, kk));
            }
            if (q == 0 || q == 1) {   // load B fragments for nh=q (4 reads)
                #pragma unroll
                for (int n2 = 0; n2 < 2; n2++)
                    #pragma unroll
                    for (int kk = 0; kk < 2; kk++)
                        bfr[q][n2][kk] = ld_bf8(smem + 65536 + bs * 32768 + (wc >> 1) * 16384 +
                                                rdoff((wc & 1) * 64 + (q * 2 + n2) * 16 + lr, kk));
            }
            __builtin_amdgcn_sched_barrier(0);
            __builtin_amdgcn_s_barrier();
            asm volatile("s_waitcnt lgkmcnt(0)" ::: "memory");
            __builtin_amdgcn_sched_barrier(0);
            __builtin_amdgcn_s_setprio(1);
            #pragma unroll
            for (int m4 = 0; m4 < 4; m4++)
                #pragma unroll
                for (int n2 = 0; n2 < 2; n2++)
                    #pragma unroll
                    for (int kk = 0; kk < 2; kk++)
                        acc[mh * 4 + m4][nh * 2 + n2] = __builtin_amdgcn_mfma_f32_16x16x32_bf16(
                            af[m4][kk], bfr[nh][n2][kk], acc[mh * 4 + m4][nh * 2 + n2], 0, 0, 0);
            __builtin_amdgcn_s_setprio(0);
            if (p == 3 || p == 7) {   // stage into just-released buffer + counted wait
                int kts = (p == 3) ? kt2 : kt3;
                stageHT(stg_buf[p], stg_ht[p] >> 1, stg_ht[p] & 1, kts);
                __builtin_amdgcn_sched_barrier(0);
                asm volatile("s_waitcnt vmcnt(2)" ::: "memory");
                __builtin_amdgcn_sched_barrier(0);
            }
            __builtin_amdgcn_s_barrier();
        }
    }

    #pragma unroll
    for (int m = 0; m < 8; m++)
        #pragma unroll
        for (int n = 0; n < 4; n++)
            #pragma unroll
            for (int r = 0; r < 4; r++) {
                int row = bm + wr * 128 + m * 16 + g * 4 + r;
                int col = bn + wc * 64 + n * 16 + lr;
                float v = acc[m][n][r];
                if constexpr (sizeof(OUT_T) == 2) Cz[(size_t)row * N + col] = f2bf(v);
                else                              Cz[(size_t)row * N + col] = v;
            }
}

// ---------------- split-K combine: out += p0 (fp32) ----------------
__global__ void k_addp(const float* __restrict__ p0, float* __restrict__ out, int n8) {
    int i = blockIdx.x * 256 + threadIdx.x;
    if (i >= n8) return;
    const float4* a = (const float4*)p0 + (size_t)i * 2;
    float4* o = (float4*)out + (size_t)i * 2;
    float4 a0 = a[0], a1 = a[1], o0 = o[0], o1 = o[1];
    o0.x += a0.x; o0.y += a0.y; o0.z += a0.z; o0.w += a0.w;
    o1.x += a1.x; o1.y += a1.y; o1.z += a1.z; o1.w += a1.w;
    o[0] = o0; o[1] = o1;
}

// ---------------- causal GQA flash attention, 2-phase pipelined ----------------
__global__ __launch_bounds__(256)
void k_attn2(const u16* __restrict__ Qb, const u16* __restrict__ Kb,
             const u16* __restrict__ VbT, u16* __restrict__ Ab) {
    extern __shared__ __align__(16) char smem[];

    const int p = blockIdx.x, h = blockIdx.y, hk = h >> 2;
    const int tid = threadIdx.x, lane = tid & 63, wid = tid >> 6;
    const int g = lane >> 4, lr = lane & 15;
    const float scale = 0.08838834764831845f;  // 1/sqrt(128)
    const int qtA = p, qtB = 31 - p, nA = qtA + 1;
    const int NIT = 33;

    const int krow_l = lane >> 4, kc16 = lane & 15;
    const int vrow_l = lane >> 3, vc8  = lane & 7;

    u16* PsB = (u16*)(smem + 65536) + wid * 16 * 72;

    auto stage = [&](int buf, int k0) {
        u16* KsD = (u16*)smem + buf * 8192;
        u16* VtD = (u16*)(smem + 32768) + buf * 8192;
        #pragma unroll
        for (int j = 0; j < 4; j++) {
            int rowt = wid * 16 + j * 4 + krow_l;
            int c16  = kc16 ^ (rowt & 7);
            __builtin_amdgcn_global_load_lds(
                (GBUF*)(Kb + (size_t)(k0 + rowt) * LDQK + hk * DHEAD + c16 * 8),
                (LBUF*)(KsD + (wid * 16 + j * 4) * 128), 16, 0, 0);
        }
        #pragma unroll
        for (int j = 0; j < 4; j++) {
            int rowt = wid * 32 + j * 8 + vrow_l;
            int c8   = vc8 ^ (rowt & 7);
            __builtin_amdgcn_global_load_lds(
                (GBUF*)(VbT + (size_t)(hk * DHEAD + rowt) * S_LEN + k0 + c8 * 8),
                (LBUF*)(VtD + (wid * 32 + j * 8) * 64), 16, 0, 0);
        }
    };

    bf16x8 qf[4];
    f32x4 acc[8];
    float m[4], lsum[4];
    int qt = qtA, q0 = qtA * 64;

    stage(0, 0);
    asm volatile("s_waitcnt vmcnt(0)" ::: "memory");
    __builtin_amdgcn_s_barrier();

    for (int i = 0; i < NIT; i++) {
        const int kt = (i < nA) ? i : (i - nA);
        if (i + 1 < NIT) {
            int kt1 = (i + 1 < nA) ? (i + 1) : (i + 1 - nA);
            stage((i + 1) & 1, kt1 * 64);
        }
        if (i == 0 || i == nA) {
            if (i == nA) {
                #pragma unroll
                for (int n = 0; n < 8; n++)
                    #pragma unroll
                    for (int r = 0; r < 4; r++)
                        Ab[(size_t)(q0 + wid * 16 + g * 4 + r) * DMODEL + h * DHEAD + n * 16 + lr]
                            = f2bf(acc[n][r] / lsum[r]);
            }
            qt = (i == 0) ? qtA : qtB;
            q0 = qt * 64;
            const u16* qrow = Qb + (size_t)(q0 + wid * 16 + lr) * LDQK + h * DHEAD;
            #pragma unroll
            for (int c = 0; c < 4; c++) qf[c] = ld_bf8(qrow + c * 32 + g * 8);
            #pragma unroll
            for (int n = 0; n < 8; n++) acc[n] = (f32x4){0.f, 0.f, 0.f, 0.f};
            #pragma unroll
            for (int r = 0; r < 4; r++) { m[r] = -1e30f; lsum[r] = 0.f; }
        }

        const char* KsB = smem + (i & 1) * 16384;
        const char* VtB = smem + 32768 + (i & 1) * 16384;

        f32x4 sf[4];
        __builtin_amdgcn_s_setprio(1);
        #pragma unroll
        for (int st = 0; st < 4; st++) {
            f32x4 s = {0.f, 0.f, 0.f, 0.f};
            #pragma unroll
            for (int c = 0; c < 4; c++) {
                int row = st * 16 + lr;
                int cb = (c * 32 + g * 8) * 2;
                bf16x8 kf = ld_bf8(KsB + row * 256 + (cb ^ ((row & 7) << 4)));
                s = __builtin_amdgcn_mfma_f32_16x16x32_bf16(qf[c], kf, s, 0, 0, 0);
            }
            sf[st] = s;
        }
        __builtin_amdgcn_s_setprio(0);

        if (kt == qt) {
            #pragma unroll
            for (int st = 0; st < 4; st++)
                #pragma unroll
                for (int r = 0; r < 4; r++) {
                    int qg = wid * 16 + g * 4 + r;
                    int kg = st * 16 + lr;
                    sf[st][r] = (kg > qg) ? -1e30f : sf[st][r] * scale;
                }
        } else {
            #pragma unroll
            for (int st = 0; st < 4; st++)
                #pragma unroll
                for (int r = 0; r < 4; r++) sf[st][r] *= scale;
        }

        float corr[4];
        #pragma unroll
        for (int r = 0; r < 4; r++) {
            float v = fmaxf(fmaxf(sf[0][r], sf[1][r]), fmaxf(sf[2][r], sf[3][r]));
            #pragma unroll
            for (int off = 1; off < 16; off <<= 1) v = fmaxf(v, __shfl_xor(v, off, 64));
            float mn = fmaxf(m[r], v);
            corr[r] = __expf(m[r] - mn);
            m[r] = mn;
        }
        float ts[4] = {0.f, 0.f, 0.f, 0.f};
        #pragma unroll
        for (int st = 0; st < 4; st++)
            #pragma unroll
            for (int r = 0; r < 4; r++) {
                float pv = __expf(sf[st][r] - m[r]);
                sf[st][r] = pv;
                ts[r] += pv;
            }
        #pragma unroll
        for (int r = 0; r < 4; r++) {
            #pragma unroll
            for (int off = 1; off < 16; off <<= 1) ts[r] += __shfl_xor(ts[r], off, 64);
            lsum[r] = lsum[r] * corr[r] + ts[r];
        }
        #pragma unroll
        for (int n = 0; n < 8; n++)
            #pragma unroll
            for (int r = 0; r < 4; r++) acc[n][r] *= corr[r];

        #pragma unroll
        for (int st = 0; st < 4; st++)
            #pragma unroll
            for (int r = 0; r < 4; r++)
                PsB[(g * 4 + r) * 72 + st * 16 + lr] = f2bf(sf[st][r]);
        asm volatile("s_waitcnt lgkmcnt(0)" ::: "memory");

        __builtin_amdgcn_s_setprio(1);
        #pragma unroll
        for (int c2 = 0; c2 < 2; c2++) {
            bf16x8 pa = ld_bf8(PsB + lr * 72 + c2 * 32 + g * 8);
            #pragma unroll
            for (int n = 0; n < 8; n++) {
                int row = n * 16 + lr;
                int cb = (c2 * 32 + g * 8) * 2;
                bf16x8 vf = ld_bf8(VtB + row * 128 + (cb ^ ((row & 7) << 4)));
                acc[n] = __builtin_amdgcn_mfma_f32_16x16x32_bf16(pa, vf, acc[n], 0, 0, 0);
            }
        }
        __builtin_amdgcn_s_setprio(0);

        asm volatile("s_waitcnt lgkmcnt(0)" ::: "memory");
        __builtin_amdgcn_sched_barrier(0);
        asm volatile("s_waitcnt vmcnt(0)" ::: "memory");
        __builtin_amdgcn_s_barrier();
    }

    #pragma unroll
    for (int n = 0; n < 8; n++)
        #pragma unroll
        for (int r = 0; r < 4; r++)
            Ab[(size_t)(q0 + wid * 16 + g * 4 + r) * DMODEL + h * DHEAD + n * 16 + lr]
                = f2bf(acc[n][r] / lsum[r]);
}

extern "C" void kernel_launch(void* const* d_in, const int* in_sizes, int n_in,
                              void* d_out, int out_size, void* d_ws, size_t ws_size,
                              hipStream_t stream) {
    const float* hidden = (const float*)d_in[0];
    const float* cosT   = (const float*)d_in[1];
    const float* sinT   = (const float*)d_in[2];
    // d_in[3] attention_mask: known causal, implemented directly
    const float* Wq = (const float*)d_in[4];
    const float* Wk = (const float*)d_in[5];
    const float* Wv = (const float*)d_in[6];
    const float* Wo = (const float*)d_in[7];
    float* out = (float*)d_out;
    char* ws = (char*)d_ws;

    // workspace (peak 120 MB):
    //   [0,16)    Xbf [2048][4096] bf16; later reused as Ab
    //   [16,64)   WqkvT [6144][4096] bf16 (dead after QKV GEMM);
    //             then VbT @[16,20); then split-K partial0 (f32, 32MB) @[20,52)
    //   [64,96)   WoT [4096][4096] bf16
    //   [96,120)  QKVb [2048][6144] bf16
    u16*   Xbf   = (u16*)ws;
    u16*   WqkvT = (u16*)(ws + (16u << 20));
    u16*   VbT   = (u16*)(ws + (16u << 20));        // alias: valid after QKV GEMM
    float* P0    = (float*)(ws + (20u << 20));      // alias: valid after attention
    u16*   WoT   = (u16*)(ws + (64u << 20));
    u16*   QKVb  = (u16*)(ws + (96u << 20));
    u16*   Ab    = Xbf;

    k_cvt<<<dim3((S_LEN * DMODEL / 8) / 256), 256, 0, stream>>>(hidden, Xbf, S_LEN * DMODEL / 8);
    k_transpose_bf16<float><<<dim3(4096 / 32, 4096 / 32), 256, 0, stream>>>(Wq, WqkvT, 4096, 4096, 4096);
    k_transpose_bf16<float><<<dim3(1024 / 32, 4096 / 32), 256, 0, stream>>>(Wk, WqkvT + (size_t)4096 * 4096, 4096, 1024, 1024);
    k_transpose_bf16<float><<<dim3(1024 / 32, 4096 / 32), 256, 0, stream>>>(Wv, WqkvT + (size_t)5120 * 4096, 4096, 1024, 1024);
    k_transpose_bf16<float><<<dim3(4096 / 32, 4096 / 32), 256, 0, stream>>>(Wo, WoT, 4096, 4096, 4096);

    hipFuncSetAttribute((const void*)k_gemm256<u16>,  hipFuncAttributeMaxDynamicSharedMemorySize, 131072);
    hipFuncSetAttribute((const void*)k_gemm256<float>, hipFuncAttributeMaxDynamicSharedMemorySize, 131072);

    // fused QKV projection: [2048][4096] x [6144][4096]^T -> [2048][6144]; 192 wgs
    k_gemm256<u16><<<192, 512, 131072, stream>>>(Xbf, WqkvT, QKVb, QKVb, 2048, 6144, 4096, 8, 24, 4096);

    // RoPE on Q (cols 0..4095) and K (cols 4096..5119)
    k_rope<<<(2048 * 32 * 64) / 256, 256, 0, stream>>>(QKVb, cosT, sinT, 32, LDQK);
    k_rope<<<(2048 * 8 * 64) / 256, 256, 0, stream>>>(QKVb + 4096, cosT, sinT, 8, LDQK);

    // V^T (cols 5120..6143 of QKVb) -> VbT [1024][2048]
    k_transpose_bf16<u16><<<dim3(1024 / 32, 2048 / 32), 256, 0, stream>>>(QKVb + 5120, VbT, 2048, 1024, LDQK);

    // attention: 16 q-tile pairs x 32 heads, 74752 B dynamic LDS
    hipFuncSetAttribute((const void*)k_attn2, hipFuncAttributeMaxDynamicSharedMemorySize, 74752);
    k_attn2<<<dim3(16, 32), 256, 74752, stream>>>(QKVb, QKVb + 4096, VbT, Ab);

    // output projection, split-K=2: kz=0 -> P0 (ws), kz=1 -> out; then out += P0
    k_gemm256<float><<<256, 512, 131072, stream>>>(Ab, WoT, P0, out, 2048, 4096, 4096, 8, 16, 2048);
    k_addp<<<(2048 * 4096 / 8) / 256, 256, 0, stream>>>(P0, out, 2048 * 4096 / 8);
}

// Round 6
// 446.197 us; speedup vs baseline: 1.1466x; 1.0386x over previous
//
#include <hip/hip_runtime.h>
#include <hip/hip_bf16.h>
#include <stdint.h>

typedef unsigned short u16;
typedef unsigned int u32;
typedef __bf16 bf16x8 __attribute__((ext_vector_type(8)));
typedef float f32x4 __attribute__((ext_vector_type(4)));
typedef u16 u16x8 __attribute__((ext_vector_type(8)));

#define S_LEN 2048
#define DMODEL 4096
#define NHEADS 32
#define NKVH 8
#define DHEAD 128
#define LDQK 6144   // row stride of fused QKV activation buffer

__device__ __forceinline__ float bf2f(u16 x) {
    union { u32 i; float f; } u; u.i = ((u32)x) << 16; return u.f;
}
__device__ __forceinline__ u16 f2bf(float f) {
    union { float f; u32 i; } u; u.f = f;
    u32 x = u.i;
    return (u16)((x + 0x7fffu + ((x >> 16) & 1u)) >> 16);
}
__device__ __forceinline__ bf16x8 ld_bf8(const void* p) {
    int4 v = *(const int4*)p;
    return __builtin_bit_cast(bf16x8, v);
}

// ---------------- fp32 -> bf16 elementwise ----------------
__global__ void k_cvt(const float* __restrict__ in, u16* __restrict__ out, int n8) {
    int i = blockIdx.x * 256 + threadIdx.x;
    if (i >= n8) return;
    const float4* p = (const float4*)in + (size_t)i * 2;
    float4 a = p[0], b = p[1];
    u16x8 o;
    o[0]=f2bf(a.x); o[1]=f2bf(a.y); o[2]=f2bf(a.z); o[3]=f2bf(a.w);
    o[4]=f2bf(b.x); o[5]=f2bf(b.y); o[6]=f2bf(b.z); o[7]=f2bf(b.w);
    *((u16x8*)out + i) = o;
}

// ---------------- transpose (+convert) to bf16: in[R][C] (ldin) -> out[C][R] ----------------
template<typename TIN>
__global__ void k_transpose_bf16(const TIN* __restrict__ in, u16* __restrict__ out,
                                 int R, int C, int ldin) {
    __shared__ u16 tile[32][33];
    int c0 = blockIdx.x * 32, r0 = blockIdx.y * 32;
    int tx = threadIdx.x & 31, ty = threadIdx.x >> 5;
    #pragma unroll
    for (int i = 0; i < 4; i++) {
        int r = ty + i * 8;
        TIN v = in[(size_t)(r0 + r) * ldin + c0 + tx];
        if constexpr (sizeof(TIN) == 4) tile[r][tx] = f2bf((float)v);
        else tile[r][tx] = (u16)v;
    }
    __syncthreads();
    #pragma unroll
    for (int i = 0; i < 4; i++) {
        int r = ty + i * 8;
        out[(size_t)(c0 + r) * R + r0 + tx] = tile[tx][r];
    }
}

// ---------------- RoPE in place on [S][nh*128] bf16 (row stride ld) ----------------
__global__ void k_rope(u16* __restrict__ X, const float* __restrict__ cosT,
                       const float* __restrict__ sinT, int nh, int ld) {
    int idx = blockIdx.x * 256 + threadIdx.x;
    int d = idx & 63;
    int h = (idx >> 6) % nh;
    int s = idx / (64 * nh);
    u16* p = X + (size_t)s * ld + h * DHEAD;
    float x1 = bf2f(p[d]), x2 = bf2f(p[d + 64]);
    float c1 = cosT[s * DHEAD + d],      s1 = sinT[s * DHEAD + d];
    float c2 = cosT[s * DHEAD + d + 64], s2 = sinT[s * DHEAD + d + 64];
    p[d]      = f2bf(x1 * c1 - x2 * s1);
    p[d + 64] = f2bf(x2 * c2 + x1 * s2);
}

typedef const __attribute__((address_space(1))) u32 GBUF;
typedef __attribute__((address_space(3))) u32 LBUF;

// ---------------- 256x256 8-phase GEMM ----------------
// C = A[M][K] x Bt[N][K]^T over K-slice [kz*k_len, (kz+1)*k_len).
// 512 threads = 8 waves (2M x 4N); per-wave 128x64 out. LDS 128KB:
// A[buf][half][128][64]u16 @0, B same @65536. 3-bit XOR swizzle (chunk^=(row&7))
// on ds_read, inverse on global SOURCE, linear LDS dest — verified conflict-free
// (R4: SQ_LDS_BANK_CONFLICT=0).
// R6 stage schedule (fixes R5 race): A's staging "half" is selected by wr, so
// BOTH A halves are read at q0 (rows 0-63) AND q2 (rows 64-127) -> A halves
// free only after p2/p6; B halves free after p1/p5 (q0: rows 0-31,64-95;
// q1: rows 32-63,96-127).
//   p:   0      1      2      3      4      5      6      7
//   stg  b1.A0  b1.A1  b0.B0  b0.B1  b0.A0  b0.A1  b1.B0  b1.B1
//   kt   2t+1   2t+1   2t+2   2t+2   2t+2   2t+2   2t+3   2t+3
// Per-wave outstanding: 4 at p0 entry, +2/phase -> 12 at p3-end; vmcnt(4)
// drains exactly buf1@kt(2t+1) (oldest drained >=2.5 phases old); symmetric
// vmcnt(4) at p7-end drains exactly buf0@kt(2t+2). Every stage is issued >=1
// phase after the end-barrier following its region's last ds_read (WAR-safe:
// each wave's lgkmcnt(0) precedes its end-barrier).
template<typename OUT_T>
__global__ __launch_bounds__(512, 2)
void k_gemm256(const u16* __restrict__ A, const u16* __restrict__ Bt,
               OUT_T* __restrict__ C0, OUT_T* __restrict__ C1,
               int M, int N, int K, int mtiles, int ntiles, int k_len) {
    extern __shared__ __align__(16) char smem[];

    const int nwg = gridDim.x;
    const int cpx = nwg >> 3;                       // nwg % 8 == 0 by launch
    const int flat = blockIdx.x;
    const int swz = (flat & 7) * cpx + (flat >> 3); // XCD-aware swizzle (T1)
    const int tile = swz % (mtiles * ntiles);
    const int kz = swz / (mtiles * ntiles);
    const int bm = (tile / ntiles) * 256, bn = (tile % ntiles) * 256;
    const int k0b = kz * k_len;
    OUT_T* __restrict__ Cz = kz ? C1 : C0;

    const int tid = threadIdx.x, lane = tid & 63, wid = tid >> 6;
    const int wr = wid >> 2, wc = wid & 3;
    const int g = lane >> 4, lr = lane & 15;

    // staging chunk precompute (2 chunks/thread/half-tile), 3-bit inverse swizzle on source
    const u16* srcA[2]; const u16* srcB[2]; u32 ldsl[2];
    #pragma unroll
    for (int j = 0; j < 2; j++) {
        int c = j * 512 + tid;                       // 0..1023
        int rowc = c >> 3;
        int colsw = (c & 7) ^ (rowc & 7);            // inverse-swizzled source col (16B units)
        srcA[j] = A  + (size_t)(bm + rowc) * K + k0b + colsw * 8;
        srcB[j] = Bt + (size_t)(bn + rowc) * K + k0b + colsw * 8;
        ldsl[j] = (u32)(j * 512 + wid * 64) * 16;    // linear LDS dest (uniform per wave)
    }

    auto stageHT = [&](int buf, int kind, int half, int kt) {
        #pragma unroll
        for (int j = 0; j < 2; j++) {
            const u16* src = (kind ? srcB[j] : srcA[j]) + (size_t)half * 128 * K + kt * 64;
            u32 off = (u32)kind * 65536 + (u32)buf * 32768 + (u32)half * 16384 + ldsl[j];
            __builtin_amdgcn_global_load_lds((GBUF*)src, (LBUF*)(smem + off), 16, 0, 0);
        }
    };

    // swizzled ds_read byte offset within a [128][64]u16 half-tile
    auto rdoff = [&](int row, int kk) -> u32 {
        return (u32)(row * 128 + ((((kk << 2) + g) ^ (row & 7)) << 4));
    };

    f32x4 acc[8][4] = {};
    bf16x8 af[4][2], bfr[2][2][2];

    const int NT = k_len >> 6;                       // 64-wide K-tiles, NT even

    // prologue: b0.{A0,A1,B0,B1}@kt0 (8 loads), b1.{B0,B1}@kt1 (4 loads);
    // vmcnt(4) drains exactly the b0 eight -> enter loop with 4 outstanding
    // (exact steady state: b1.B0,B1 pending as if issued at p6,p7 of iter -1).
    stageHT(0, 0, 0, 0); stageHT(0, 0, 1, 0); stageHT(0, 1, 0, 0); stageHT(0, 1, 1, 0);
    stageHT(1, 1, 0, 1); stageHT(1, 1, 1, 1);
    __builtin_amdgcn_sched_barrier(0);
    asm volatile("s_waitcnt vmcnt(4)" ::: "memory");
    __builtin_amdgcn_sched_barrier(0);
    __builtin_amdgcn_s_barrier();

    // stage maps: p -> {buf, kind(0=A,1=B), half}
    const int stg_buf[8]  = {1,1,0,0,0,0,1,1};
    const int stg_kind[8] = {0,0,1,1,0,0,1,1};
    const int stg_half[8] = {0,1,0,1,0,1,0,1};

    for (int t = 0; t < (NT >> 1); t++) {
        const int kt1 = 2 * t + 1;                       // never wraps
        int kt2 = 2 * t + 2; if (kt2 >= NT) kt2 -= NT;   // wrapped prefetch keeps
        int kt3 = 2 * t + 3; if (kt3 >= NT) kt3 -= NT;   // vmcnt arithmetic exact
        #pragma unroll
        for (int p = 0; p < 8; p++) {
            const int q = p & 3, bs = p >> 2;
            const int mh = q >> 1, nh = q & 1;
            // ---- ds_reads for this phase ----
            if (q == 0 || q == 2) {   // new mh: load A fragments (8 reads)
                #pragma unroll
                for (int m4 = 0; m4 < 4; m4++)
                    #pragma unroll
                    for (int kk = 0; kk < 2; kk++)
                        af[m4][kk] = ld_bf8(smem + bs * 32768 + wr * 16384 +
                                            rdoff((mh * 4 + m4) * 16 + lr, kk));
            }
            if (q == 0 || q == 1) {   // load B fragments for nh=q (4 reads)
                #pragma unroll
                for (int n2 = 0; n2 < 2; n2++)
                    #pragma unroll
                    for (int kk = 0; kk < 2; kk++)
                        bfr[q][n2][kk] = ld_bf8(smem + 65536 + bs * 32768 + (wc >> 1) * 16384 +
                                                rdoff((wc & 1) * 64 + (q * 2 + n2) * 16 + lr, kk));
            }
            // ---- stage one half-tile (region freed >=1 phase ago) ----
            {
                int kts = (p < 2) ? kt1 : (p < 6 ? kt2 : kt3);
                stageHT(stg_buf[p], stg_kind[p], stg_half[p], kts);
            }
            __builtin_amdgcn_s_barrier();
            asm volatile("s_waitcnt lgkmcnt(0)" ::: "memory");
            __builtin_amdgcn_s_setprio(1);
            #pragma unroll
            for (int m4 = 0; m4 < 4; m4++)
                #pragma unroll
                for (int n2 = 0; n2 < 2; n2++)
                    #pragma unroll
                    for (int kk = 0; kk < 2; kk++)
                        acc[mh * 4 + m4][nh * 2 + n2] = __builtin_amdgcn_mfma_f32_16x16x32_bf16(
                            af[m4][kk], bfr[nh][n2][kk], acc[mh * 4 + m4][nh * 2 + n2], 0, 0, 0);
            __builtin_amdgcn_s_setprio(0);
            if (q == 3) {             // counted wait: drains loads >=2.5 phases old
                __builtin_amdgcn_sched_barrier(0);
                asm volatile("s_waitcnt vmcnt(4)" ::: "memory");
                __builtin_amdgcn_sched_barrier(0);
            }
            __builtin_amdgcn_s_barrier();
        }
    }

    #pragma unroll
    for (int m = 0; m < 8; m++)
        #pragma unroll
        for (int n = 0; n < 4; n++)
            #pragma unroll
            for (int r = 0; r < 4; r++) {
                int row = bm + wr * 128 + m * 16 + g * 4 + r;
                int col = bn + wc * 64 + n * 16 + lr;
                float v = acc[m][n][r];
                if constexpr (sizeof(OUT_T) == 2) Cz[(size_t)row * N + col] = f2bf(v);
                else                              Cz[(size_t)row * N + col] = v;
            }
}

// ---------------- split-K combine: out += p0 (fp32) ----------------
__global__ void k_addp(const float* __restrict__ p0, float* __restrict__ out, int n8) {
    int i = blockIdx.x * 256 + threadIdx.x;
    if (i >= n8) return;
    const float4* a = (const float4*)p0 + (size_t)i * 2;
    float4* o = (float4*)out + (size_t)i * 2;
    float4 a0 = a[0], a1 = a[1], o0 = o[0], o1 = o[1];
    o0.x += a0.x; o0.y += a0.y; o0.z += a0.z; o0.w += a0.w;
    o1.x += a1.x; o1.y += a1.y; o1.z += a1.z; o1.w += a1.w;
    o[0] = o0; o[1] = o1;
}

// ---------------- causal GQA flash attention, 2-phase pipelined ----------------
__global__ __launch_bounds__(256)
void k_attn2(const u16* __restrict__ Qb, const u16* __restrict__ Kb,
             const u16* __restrict__ VbT, u16* __restrict__ Ab) {
    extern __shared__ __align__(16) char smem[];

    const int p = blockIdx.x, h = blockIdx.y, hk = h >> 2;
    const int tid = threadIdx.x, lane = tid & 63, wid = tid >> 6;
    const int g = lane >> 4, lr = lane & 15;
    const float scale = 0.08838834764831845f;  // 1/sqrt(128)
    const int qtA = p, qtB = 31 - p, nA = qtA + 1;
    const int NIT = 33;

    const int krow_l = lane >> 4, kc16 = lane & 15;
    const int vrow_l = lane >> 3, vc8  = lane & 7;

    u16* PsB = (u16*)(smem + 65536) + wid * 16 * 72;

    auto stage = [&](int buf, int k0) {
        u16* KsD = (u16*)smem + buf * 8192;
        u16* VtD = (u16*)(smem + 32768) + buf * 8192;
        #pragma unroll
        for (int j = 0; j < 4; j++) {
            int rowt = wid * 16 + j * 4 + krow_l;
            int c16  = kc16 ^ (rowt & 7);
            __builtin_amdgcn_global_load_lds(
                (GBUF*)(Kb + (size_t)(k0 + rowt) * LDQK + hk * DHEAD + c16 * 8),
                (LBUF*)(KsD + (wid * 16 + j * 4) * 128), 16, 0, 0);
        }
        #pragma unroll
        for (int j = 0; j < 4; j++) {
            int rowt = wid * 32 + j * 8 + vrow_l;
            int c8   = vc8 ^ (rowt & 7);
            __builtin_amdgcn_global_load_lds(
                (GBUF*)(VbT + (size_t)(hk * DHEAD + rowt) * S_LEN + k0 + c8 * 8),
                (LBUF*)(VtD + (wid * 32 + j * 8) * 64), 16, 0, 0);
        }
    };

    bf16x8 qf[4];
    f32x4 acc[8];
    float m[4], lsum[4];
    int qt = qtA, q0 = qtA * 64;

    stage(0, 0);
    asm volatile("s_waitcnt vmcnt(0)" ::: "memory");
    __builtin_amdgcn_s_barrier();

    for (int i = 0; i < NIT; i++) {
        const int kt = (i < nA) ? i : (i - nA);
        if (i + 1 < NIT) {
            int kt1 = (i + 1 < nA) ? (i + 1) : (i + 1 - nA);
            stage((i + 1) & 1, kt1 * 64);
        }
        if (i == 0 || i == nA) {
            if (i == nA) {
                #pragma unroll
                for (int n = 0; n < 8; n++)
                    #pragma unroll
                    for (int r = 0; r < 4; r++)
                        Ab[(size_t)(q0 + wid * 16 + g * 4 + r) * DMODEL + h * DHEAD + n * 16 + lr]
                            = f2bf(acc[n][r] / lsum[r]);
            }
            qt = (i == 0) ? qtA : qtB;
            q0 = qt * 64;
            const u16* qrow = Qb + (size_t)(q0 + wid * 16 + lr) * LDQK + h * DHEAD;
            #pragma unroll
            for (int c = 0; c < 4; c++) qf[c] = ld_bf8(qrow + c * 32 + g * 8);
            #pragma unroll
            for (int n = 0; n < 8; n++) acc[n] = (f32x4){0.f, 0.f, 0.f, 0.f};
            #pragma unroll
            for (int r = 0; r < 4; r++) { m[r] = -1e30f; lsum[r] = 0.f; }
        }

        const char* KsB = smem + (i & 1) * 16384;
        const char* VtB = smem + 32768 + (i & 1) * 16384;

        f32x4 sf[4];
        __builtin_amdgcn_s_setprio(1);
        #pragma unroll
        for (int st = 0; st < 4; st++) {
            f32x4 s = {0.f, 0.f, 0.f, 0.f};
            #pragma unroll
            for (int c = 0; c < 4; c++) {
                int row = st * 16 + lr;
                int cb = (c * 32 + g * 8) * 2;
                bf16x8 kf = ld_bf8(KsB + row * 256 + (cb ^ ((row & 7) << 4)));
                s = __builtin_amdgcn_mfma_f32_16x16x32_bf16(qf[c], kf, s, 0, 0, 0);
            }
            sf[st] = s;
        }
        __builtin_amdgcn_s_setprio(0);

        if (kt == qt) {
            #pragma unroll
            for (int st = 0; st < 4; st++)
                #pragma unroll
                for (int r = 0; r < 4; r++) {
                    int qg = wid * 16 + g * 4 + r;
                    int kg = st * 16 + lr;
                    sf[st][r] = (kg > qg) ? -1e30f : sf[st][r] * scale;
                }
        } else {
            #pragma unroll
            for (int st = 0; st < 4; st++)
                #pragma unroll
                for (int r = 0; r < 4; r++) sf[st][r] *= scale;
        }

        float corr[4];
        #pragma unroll
        for (int r = 0; r < 4; r++) {
            float v = fmaxf(fmaxf(sf[0][r], sf[1][r]), fmaxf(sf[2][r], sf[3][r]));
            #pragma unroll
            for (int off = 1; off < 16; off <<= 1) v = fmaxf(v, __shfl_xor(v, off, 64));
            float mn = fmaxf(m[r], v);
            corr[r] = __expf(m[r] - mn);
            m[r] = mn;
        }
        float ts[4] = {0.f, 0.f, 0.f, 0.f};
        #pragma unroll
        for (int st = 0; st < 4; st++)
            #pragma unroll
            for (int r = 0; r < 4; r++) {
                float pv = __expf(sf[st][r] - m[r]);
                sf[st][r] = pv;
                ts[r] += pv;
            }
        #pragma unroll
        for (int r = 0; r < 4; r++) {
            #pragma unroll
            for (int off = 1; off < 16; off <<= 1) ts[r] += __shfl_xor(ts[r], off, 64);
            lsum[r] = lsum[r] * corr[r] + ts[r];
        }
        #pragma unroll
        for (int n = 0; n < 8; n++)
            #pragma unroll
            for (int r = 0; r < 4; r++) acc[n][r] *= corr[r];

        #pragma unroll
        for (int st = 0; st < 4; st++)
            #pragma unroll
            for (int r = 0; r < 4; r++)
                PsB[(g * 4 + r) * 72 + st * 16 + lr] = f2bf(sf[st][r]);
        asm volatile("s_waitcnt lgkmcnt(0)" ::: "memory");

        __builtin_amdgcn_s_setprio(1);
        #pragma unroll
        for (int c2 = 0; c2 < 2; c2++) {
            bf16x8 pa = ld_bf8(PsB + lr * 72 + c2 * 32 + g * 8);
            #pragma unroll
            for (int n = 0; n < 8; n++) {
                int row = n * 16 + lr;
                int cb = (c2 * 32 + g * 8) * 2;
                bf16x8 vf = ld_bf8(VtB + row * 128 + (cb ^ ((row & 7) << 4)));
                acc[n] = __builtin_amdgcn_mfma_f32_16x16x32_bf16(pa, vf, acc[n], 0, 0, 0);
            }
        }
        __builtin_amdgcn_s_setprio(0);

        asm volatile("s_waitcnt lgkmcnt(0)" ::: "memory");
        __builtin_amdgcn_sched_barrier(0);
        asm volatile("s_waitcnt vmcnt(0)" ::: "memory");
        __builtin_amdgcn_s_barrier();
    }

    #pragma unroll
    for (int n = 0; n < 8; n++)
        #pragma unroll
        for (int r = 0; r < 4; r++)
            Ab[(size_t)(q0 + wid * 16 + g * 4 + r) * DMODEL + h * DHEAD + n * 16 + lr]
                = f2bf(acc[n][r] / lsum[r]);
}

extern "C" void kernel_launch(void* const* d_in, const int* in_sizes, int n_in,
                              void* d_out, int out_size, void* d_ws, size_t ws_size,
                              hipStream_t stream) {
    const float* hidden = (const float*)d_in[0];
    const float* cosT   = (const float*)d_in[1];
    const float* sinT   = (const float*)d_in[2];
    // d_in[3] attention_mask: known causal, implemented directly
    const float* Wq = (const float*)d_in[4];
    const float* Wk = (const float*)d_in[5];
    const float* Wv = (const float*)d_in[6];
    const float* Wo = (const float*)d_in[7];
    float* out = (float*)d_out;
    char* ws = (char*)d_ws;

    // workspace (peak 120 MB):
    //   [0,16)    Xbf [2048][4096] bf16; later reused as Ab
    //   [16,64)   WqkvT [6144][4096] bf16 (dead after QKV GEMM);
    //             then VbT @[16,20); then split-K partial0 (f32, 32MB) @[20,52)
    //   [64,96)   WoT [4096][4096] bf16
    //   [96,120)  QKVb [2048][6144] bf16
    u16*   Xbf   = (u16*)ws;
    u16*   WqkvT = (u16*)(ws + (16u << 20));
    u16*   VbT   = (u16*)(ws + (16u << 20));        // alias: valid after QKV GEMM
    float* P0    = (float*)(ws + (20u << 20));      // alias: valid after attention
    u16*   WoT   = (u16*)(ws + (64u << 20));
    u16*   QKVb  = (u16*)(ws + (96u << 20));
    u16*   Ab    = Xbf;

    k_cvt<<<dim3((S_LEN * DMODEL / 8) / 256), 256, 0, stream>>>(hidden, Xbf, S_LEN * DMODEL / 8);
    k_transpose_bf16<float><<<dim3(4096 / 32, 4096 / 32), 256, 0, stream>>>(Wq, WqkvT, 4096, 4096, 4096);
    k_transpose_bf16<float><<<dim3(1024 / 32, 4096 / 32), 256, 0, stream>>>(Wk, WqkvT + (size_t)4096 * 4096, 4096, 1024, 1024);
    k_transpose_bf16<float><<<dim3(1024 / 32, 4096 / 32), 256, 0, stream>>>(Wv, WqkvT + (size_t)5120 * 4096, 4096, 1024, 1024);
    k_transpose_bf16<float><<<dim3(4096 / 32, 4096 / 32), 256, 0, stream>>>(Wo, WoT, 4096, 4096, 4096);

    hipFuncSetAttribute((const void*)k_gemm256<u16>,  hipFuncAttributeMaxDynamicSharedMemorySize, 131072);
    hipFuncSetAttribute((const void*)k_gemm256<float>, hipFuncAttributeMaxDynamicSharedMemorySize, 131072);

    // fused QKV projection: [2048][4096] x [6144][4096]^T -> [2048][6144]; 192 wgs
    k_gemm256<u16><<<192, 512, 131072, stream>>>(Xbf, WqkvT, QKVb, QKVb, 2048, 6144, 4096, 8, 24, 4096);

    // RoPE on Q (cols 0..4095) and K (cols 4096..5119)
    k_rope<<<(2048 * 32 * 64) / 256, 256, 0, stream>>>(QKVb, cosT, sinT, 32, LDQK);
    k_rope<<<(2048 * 8 * 64) / 256, 256, 0, stream>>>(QKVb + 4096, cosT, sinT, 8, LDQK);

    // V^T (cols 5120..6143 of QKVb) -> VbT [1024][2048]
    k_transpose_bf16<u16><<<dim3(1024 / 32, 2048 / 32), 256, 0, stream>>>(QKVb + 5120, VbT, 2048, 1024, LDQK);

    // attention: 16 q-tile pairs x 32 heads, 74752 B dynamic LDS
    hipFuncSetAttribute((const void*)k_attn2, hipFuncAttributeMaxDynamicSharedMemorySize, 74752);
    k_attn2<<<dim3(16, 32), 256, 74752, stream>>>(QKVb, QKVb + 4096, VbT, Ab);

    // output projection, split-K=2: kz=0 -> P0 (ws), kz=1 -> out; then out += P0
    k_gemm256<float><<<256, 512, 131072, stream>>>(Ab, WoT, P0, out, 2048, 4096, 4096, 8, 16, 2048);
    k_addp<<<(2048 * 4096 / 8) / 256, 256, 0, stream>>>(P0, out, 2048 * 4096 / 8);
}

// Round 7
// 372.520 us; speedup vs baseline: 1.3734x; 1.1978x over previous
//
#include <hip/hip_runtime.h>
#include <hip/hip_bf16.h>
#include <stdint.h>

typedef unsigned short u16;
typedef unsigned int u32;
typedef __bf16 bf16x8 __attribute__((ext_vector_type(8)));
typedef float f32x4 __attribute__((ext_vector_type(4)));
typedef u16 u16x8 __attribute__((ext_vector_type(8)));

#define S_LEN 2048
#define DMODEL 4096
#define NHEADS 32
#define NKVH 8
#define DHEAD 128
#define LDQK 6144   // row stride of fused QKV activation buffer

__device__ __forceinline__ float bf2f(u16 x) {
    union { u32 i; float f; } u; u.i = ((u32)x) << 16; return u.f;
}
__device__ __forceinline__ u16 f2bf(float f) {
    union { float f; u32 i; } u; u.f = f;
    u32 x = u.i;
    return (u16)((x + 0x7fffu + ((x >> 16) & 1u)) >> 16);
}
__device__ __forceinline__ bf16x8 ld_bf8(const void* p) {
    int4 v = *(const int4*)p;
    return __builtin_bit_cast(bf16x8, v);
}

// ---------------- fp32 -> bf16 elementwise ----------------
__global__ void k_cvt(const float* __restrict__ in, u16* __restrict__ out, int n8) {
    int i = blockIdx.x * 256 + threadIdx.x;
    if (i >= n8) return;
    const float4* p = (const float4*)in + (size_t)i * 2;
    float4 a = p[0], b = p[1];
    u16x8 o;
    o[0]=f2bf(a.x); o[1]=f2bf(a.y); o[2]=f2bf(a.z); o[3]=f2bf(a.w);
    o[4]=f2bf(b.x); o[5]=f2bf(b.y); o[6]=f2bf(b.z); o[7]=f2bf(b.w);
    *((u16x8*)out + i) = o;
}

// ---------------- transpose (+convert) to bf16: in[R][C] (ldin) -> out[C][R] ----------------
template<typename TIN>
__global__ void k_transpose_bf16(const TIN* __restrict__ in, u16* __restrict__ out,
                                 int R, int C, int ldin) {
    __shared__ u16 tile[32][33];
    int c0 = blockIdx.x * 32, r0 = blockIdx.y * 32;
    int tx = threadIdx.x & 31, ty = threadIdx.x >> 5;
    #pragma unroll
    for (int i = 0; i < 4; i++) {
        int r = ty + i * 8;
        TIN v = in[(size_t)(r0 + r) * ldin + c0 + tx];
        if constexpr (sizeof(TIN) == 4) tile[r][tx] = f2bf((float)v);
        else tile[r][tx] = (u16)v;
    }
    __syncthreads();
    #pragma unroll
    for (int i = 0; i < 4; i++) {
        int r = ty + i * 8;
        out[(size_t)(c0 + r) * R + r0 + tx] = tile[tx][r];
    }
}

// ---------------- RoPE in place on [S][nh*128] bf16 (row stride ld) ----------------
__global__ void k_rope(u16* __restrict__ X, const float* __restrict__ cosT,
                       const float* __restrict__ sinT, int nh, int ld) {
    int idx = blockIdx.x * 256 + threadIdx.x;
    int d = idx & 63;
    int h = (idx >> 6) % nh;
    int s = idx / (64 * nh);
    u16* p = X + (size_t)s * ld + h * DHEAD;
    float x1 = bf2f(p[d]), x2 = bf2f(p[d + 64]);
    float c1 = cosT[s * DHEAD + d],      s1 = sinT[s * DHEAD + d];
    float c2 = cosT[s * DHEAD + d + 64], s2 = sinT[s * DHEAD + d + 64];
    p[d]      = f2bf(x1 * c1 - x2 * s1);
    p[d + 64] = f2bf(x2 * c2 + x1 * s2);
}

typedef const __attribute__((address_space(1))) u32 GBUF;
typedef __attribute__((address_space(3))) u32 LBUF;

// ---------------- m97-structure 128x128 GEMM, BK=64, swizzled LDS ----------------
// C[M][N] = A[M][K] x Bt[N][K]^T. 256 threads = 4 waves (2x2), per-wave 64x64 out.
// Static LDS 32KB (As,Bs [128][64]u16) -> ~3 blocks/CU: __syncthreads drains are
// hidden by cross-block wave overlap (m114), unlike the 1-block/CU 8-phase try.
// 3-bit chunk XOR swizzle (chunk ^= row&7) on ds_read, inverse on global SOURCE,
// linear LDS dest — verified conflict-free + correct in R4/R6 (same geometry).
template<typename OUT_T>
__global__ __launch_bounds__(256)
void k_gemm_bt2(const u16* __restrict__ A, const u16* __restrict__ Bt,
                OUT_T* __restrict__ C, int M, int N, int K) {
    __shared__ __align__(16) u16 As[128 * 64];
    __shared__ __align__(16) u16 Bs[128 * 64];
    const int m0 = blockIdx.y * 128, n0 = blockIdx.x * 128;
    const int tid = threadIdx.x, lane = tid & 63, wid = tid >> 6;
    const int wr = wid >> 1, wc = wid & 1;
    const int g = lane >> 4, lr = lane & 15;

    // staging: 4 chunks/thread/operand; c = j*256+tid, row=c>>3, col^=(row&7)
    const u16* sA[4]; const u16* sB[4]; u32 dste[4];
    #pragma unroll
    for (int j = 0; j < 4; j++) {
        int c = j * 256 + tid;                    // 0..1023 (16B chunks)
        int row = c >> 3;
        int colsw = (c & 7) ^ (row & 7);          // inverse-swizzled source col
        sA[j] = A  + (size_t)(m0 + row) * K + colsw * 8;
        sB[j] = Bt + (size_t)(n0 + row) * K + colsw * 8;
        dste[j] = (u32)c * 8;                     // linear LDS dest (elements)
    }
    // swizzled ds_read byte offset in [128][64]u16
    auto rdoff = [&](int row, int kk) -> u32 {
        return (u32)(row * 128 + ((((kk << 2) + g) ^ (row & 7)) << 4));
    };

    f32x4 acc[4][4] = {};

    for (int k0 = 0; k0 < K; k0 += 64) {
        __syncthreads();
        #pragma unroll
        for (int j = 0; j < 4; j++)
            __builtin_amdgcn_global_load_lds((GBUF*)(sA[j] + k0), (LBUF*)(As + dste[j]), 16, 0, 0);
        #pragma unroll
        for (int j = 0; j < 4; j++)
            __builtin_amdgcn_global_load_lds((GBUF*)(sB[j] + k0), (LBUF*)(Bs + dste[j]), 16, 0, 0);
        __syncthreads();   // compiler emits vmcnt(0) drain: staged data visible

        bf16x8 af[4][2], bfv[4][2];
        #pragma unroll
        for (int i = 0; i < 4; i++)
            #pragma unroll
            for (int kk = 0; kk < 2; kk++)
                af[i][kk] = ld_bf8((const char*)As + rdoff(wr * 64 + i * 16 + lr, kk));
        #pragma unroll
        for (int n = 0; n < 4; n++)
            #pragma unroll
            for (int kk = 0; kk < 2; kk++)
                bfv[n][kk] = ld_bf8((const char*)Bs + rdoff(wc * 64 + n * 16 + lr, kk));
        #pragma unroll
        for (int i = 0; i < 4; i++)
            #pragma unroll
            for (int n = 0; n < 4; n++)
                #pragma unroll
                for (int kk = 0; kk < 2; kk++)
                    acc[i][n] = __builtin_amdgcn_mfma_f32_16x16x32_bf16(
                        af[i][kk], bfv[n][kk], acc[i][n], 0, 0, 0);
    }
    #pragma unroll
    for (int i = 0; i < 4; i++)
        #pragma unroll
        for (int n = 0; n < 4; n++)
            #pragma unroll
            for (int r = 0; r < 4; r++) {
                int row = m0 + wr * 64 + i * 16 + g * 4 + r;
                int col = n0 + wc * 64 + n * 16 + lr;
                float v = acc[i][n][r];
                if constexpr (sizeof(OUT_T) == 2) C[(size_t)row * N + col] = f2bf(v);
                else                              C[(size_t)row * N + col] = v;
            }
}

// ---------------- causal GQA flash attention, 2-phase pipelined + defer-max ----------------
__global__ __launch_bounds__(256)
void k_attn2(const u16* __restrict__ Qb, const u16* __restrict__ Kb,
             const u16* __restrict__ VbT, u16* __restrict__ Ab) {
    extern __shared__ __align__(16) char smem[];

    const int p = blockIdx.x, h = blockIdx.y, hk = h >> 2;
    const int tid = threadIdx.x, lane = tid & 63, wid = tid >> 6;
    const int g = lane >> 4, lr = lane & 15;
    const float scale = 0.08838834764831845f;  // 1/sqrt(128)
    const int qtA = p, qtB = 31 - p, nA = qtA + 1;
    const int NIT = 33;

    const int krow_l = lane >> 4, kc16 = lane & 15;
    const int vrow_l = lane >> 3, vc8  = lane & 7;

    u16* PsB = (u16*)(smem + 65536) + wid * 16 * 72;

    auto stage = [&](int buf, int k0) {
        u16* KsD = (u16*)smem + buf * 8192;
        u16* VtD = (u16*)(smem + 32768) + buf * 8192;
        #pragma unroll
        for (int j = 0; j < 4; j++) {
            int rowt = wid * 16 + j * 4 + krow_l;
            int c16  = kc16 ^ (rowt & 7);
            __builtin_amdgcn_global_load_lds(
                (GBUF*)(Kb + (size_t)(k0 + rowt) * LDQK + hk * DHEAD + c16 * 8),
                (LBUF*)(KsD + (wid * 16 + j * 4) * 128), 16, 0, 0);
        }
        #pragma unroll
        for (int j = 0; j < 4; j++) {
            int rowt = wid * 32 + j * 8 + vrow_l;
            int c8   = vc8 ^ (rowt & 7);
            __builtin_amdgcn_global_load_lds(
                (GBUF*)(VbT + (size_t)(hk * DHEAD + rowt) * S_LEN + k0 + c8 * 8),
                (LBUF*)(VtD + (wid * 32 + j * 8) * 64), 16, 0, 0);
        }
    };

    bf16x8 qf[4];
    f32x4 acc[8];
    float m[4], lsum[4];
    int qt = qtA, q0 = qtA * 64;

    stage(0, 0);
    asm volatile("s_waitcnt vmcnt(0)" ::: "memory");
    __builtin_amdgcn_s_barrier();

    for (int i = 0; i < NIT; i++) {
        const int kt = (i < nA) ? i : (i - nA);
        if (i + 1 < NIT) {
            int kt1 = (i + 1 < nA) ? (i + 1) : (i + 1 - nA);
            stage((i + 1) & 1, kt1 * 64);
        }
        if (i == 0 || i == nA) {
            if (i == nA) {
                #pragma unroll
                for (int n = 0; n < 8; n++)
                    #pragma unroll
                    for (int r = 0; r < 4; r++)
                        Ab[(size_t)(q0 + wid * 16 + g * 4 + r) * DMODEL + h * DHEAD + n * 16 + lr]
                            = f2bf(acc[n][r] / lsum[r]);
            }
            qt = (i == 0) ? qtA : qtB;
            q0 = qt * 64;
            const u16* qrow = Qb + (size_t)(q0 + wid * 16 + lr) * LDQK + h * DHEAD;
            #pragma unroll
            for (int c = 0; c < 4; c++) qf[c] = ld_bf8(qrow + c * 32 + g * 8);
            #pragma unroll
            for (int n = 0; n < 8; n++) acc[n] = (f32x4){0.f, 0.f, 0.f, 0.f};
            #pragma unroll
            for (int r = 0; r < 4; r++) { m[r] = -1e30f; lsum[r] = 0.f; }
        }

        const char* KsB = smem + (i & 1) * 16384;
        const char* VtB = smem + 32768 + (i & 1) * 16384;

        f32x4 sf[4];
        __builtin_amdgcn_s_setprio(1);
        #pragma unroll
        for (int st = 0; st < 4; st++) {
            f32x4 s = {0.f, 0.f, 0.f, 0.f};
            #pragma unroll
            for (int c = 0; c < 4; c++) {
                int row = st * 16 + lr;
                int cb = (c * 32 + g * 8) * 2;
                bf16x8 kf = ld_bf8(KsB + row * 256 + (cb ^ ((row & 7) << 4)));
                s = __builtin_amdgcn_mfma_f32_16x16x32_bf16(qf[c], kf, s, 0, 0, 0);
            }
            sf[st] = s;
        }
        __builtin_amdgcn_s_setprio(0);

        if (kt == qt) {
            #pragma unroll
            for (int st = 0; st < 4; st++)
                #pragma unroll
                for (int r = 0; r < 4; r++) {
                    int qg = wid * 16 + g * 4 + r;
                    int kg = st * 16 + lr;
                    sf[st][r] = (kg > qg) ? -1e30f : sf[st][r] * scale;
                }
        } else {
            #pragma unroll
            for (int st = 0; st < 4; st++)
                #pragma unroll
                for (int r = 0; r < 4; r++) sf[st][r] *= scale;
        }

        // ---- online softmax with defer-max (T13, THR=8) ----
        float corr[4];
        int allskip = 1;
        #pragma unroll
        for (int r = 0; r < 4; r++) {
            float v = fmaxf(fmaxf(sf[0][r], sf[1][r]), fmaxf(sf[2][r], sf[3][r]));
            #pragma unroll
            for (int off = 1; off < 16; off <<= 1) v = fmaxf(v, __shfl_xor(v, off, 64));
            bool sk = (v <= m[r] + 8.0f);      // defer: keep old max, P <= e^8
            float mn = sk ? m[r] : v;
            corr[r] = sk ? 1.0f : __expf(m[r] - mn);
            m[r] = mn;
            allskip &= (int)sk;
        }
        float ts[4] = {0.f, 0.f, 0.f, 0.f};
        #pragma unroll
        for (int st = 0; st < 4; st++)
            #pragma unroll
            for (int r = 0; r < 4; r++) {
                float pv = __expf(sf[st][r] - m[r]);
                sf[st][r] = pv;
                ts[r] += pv;
            }
        #pragma unroll
        for (int r = 0; r < 4; r++) {
            #pragma unroll
            for (int off = 1; off < 16; off <<= 1) ts[r] += __shfl_xor(ts[r], off, 64);
            lsum[r] = lsum[r] * corr[r] + ts[r];
        }
        if (!__all(allskip)) {                  // wave-uniform: skip rescale pass
            #pragma unroll
            for (int n = 0; n < 8; n++)
                #pragma unroll
                for (int r = 0; r < 4; r++) acc[n][r] *= corr[r];
        }

        #pragma unroll
        for (int st = 0; st < 4; st++)
            #pragma unroll
            for (int r = 0; r < 4; r++)
                PsB[(g * 4 + r) * 72 + st * 16 + lr] = f2bf(sf[st][r]);
        asm volatile("s_waitcnt lgkmcnt(0)" ::: "memory");

        __builtin_amdgcn_s_setprio(1);
        #pragma unroll
        for (int c2 = 0; c2 < 2; c2++) {
            bf16x8 pa = ld_bf8(PsB + lr * 72 + c2 * 32 + g * 8);
            #pragma unroll
            for (int n = 0; n < 8; n++) {
                int row = n * 16 + lr;
                int cb = (c2 * 32 + g * 8) * 2;
                bf16x8 vf = ld_bf8(VtB + row * 128 + (cb ^ ((row & 7) << 4)));
                acc[n] = __builtin_amdgcn_mfma_f32_16x16x32_bf16(pa, vf, acc[n], 0, 0, 0);
            }
        }
        __builtin_amdgcn_s_setprio(0);

        asm volatile("s_waitcnt lgkmcnt(0)" ::: "memory");
        __builtin_amdgcn_sched_barrier(0);
        asm volatile("s_waitcnt vmcnt(0)" ::: "memory");
        __builtin_amdgcn_s_barrier();
    }

    #pragma unroll
    for (int n = 0; n < 8; n++)
        #pragma unroll
        for (int r = 0; r < 4; r++)
            Ab[(size_t)(q0 + wid * 16 + g * 4 + r) * DMODEL + h * DHEAD + n * 16 + lr]
                = f2bf(acc[n][r] / lsum[r]);
}

extern "C" void kernel_launch(void* const* d_in, const int* in_sizes, int n_in,
                              void* d_out, int out_size, void* d_ws, size_t ws_size,
                              hipStream_t stream) {
    const float* hidden = (const float*)d_in[0];
    const float* cosT   = (const float*)d_in[1];
    const float* sinT   = (const float*)d_in[2];
    // d_in[3] attention_mask: known causal, implemented directly
    const float* Wq = (const float*)d_in[4];
    const float* Wk = (const float*)d_in[5];
    const float* Wv = (const float*)d_in[6];
    const float* Wo = (const float*)d_in[7];
    float* out = (float*)d_out;
    char* ws = (char*)d_ws;

    // workspace (peak 120 MB):
    //   [0,16)    Xbf [2048][4096] bf16; later reused as Ab
    //   [16,64)   WqkvT [6144][4096] bf16 (dead after QKV GEMM); VbT aliases head
    //   [64,96)   WoT [4096][4096] bf16
    //   [96,120)  QKVb [2048][6144] bf16
    u16* Xbf   = (u16*)ws;
    u16* WqkvT = (u16*)(ws + (16u << 20));
    u16* VbT   = (u16*)(ws + (16u << 20));          // alias: valid after QKV GEMM
    u16* WoT   = (u16*)(ws + (64u << 20));
    u16* QKVb  = (u16*)(ws + (96u << 20));
    u16* Ab    = Xbf;

    k_cvt<<<dim3((S_LEN * DMODEL / 8) / 256), 256, 0, stream>>>(hidden, Xbf, S_LEN * DMODEL / 8);
    k_transpose_bf16<float><<<dim3(4096 / 32, 4096 / 32), 256, 0, stream>>>(Wq, WqkvT, 4096, 4096, 4096);
    k_transpose_bf16<float><<<dim3(1024 / 32, 4096 / 32), 256, 0, stream>>>(Wk, WqkvT + (size_t)4096 * 4096, 4096, 1024, 1024);
    k_transpose_bf16<float><<<dim3(1024 / 32, 4096 / 32), 256, 0, stream>>>(Wv, WqkvT + (size_t)5120 * 4096, 4096, 1024, 1024);
    k_transpose_bf16<float><<<dim3(4096 / 32, 4096 / 32), 256, 0, stream>>>(Wo, WoT, 4096, 4096, 4096);

    // fused QKV projection: [2048][4096] x [6144][4096]^T -> [2048][6144]
    k_gemm_bt2<u16><<<dim3(6144 / 128, 2048 / 128), 256, 0, stream>>>(Xbf, WqkvT, QKVb, 2048, 6144, 4096);

    // RoPE on Q (cols 0..4095) and K (cols 4096..5119)
    k_rope<<<(2048 * 32 * 64) / 256, 256, 0, stream>>>(QKVb, cosT, sinT, 32, LDQK);
    k_rope<<<(2048 * 8 * 64) / 256, 256, 0, stream>>>(QKVb + 4096, cosT, sinT, 8, LDQK);

    // V^T (cols 5120..6143 of QKVb) -> VbT [1024][2048]
    k_transpose_bf16<u16><<<dim3(1024 / 32, 2048 / 32), 256, 0, stream>>>(QKVb + 5120, VbT, 2048, 1024, LDQK);

    // attention: 16 q-tile pairs x 32 heads, 74752 B dynamic LDS
    hipFuncSetAttribute((const void*)k_attn2, hipFuncAttributeMaxDynamicSharedMemorySize, 74752);
    k_attn2<<<dim3(16, 32), 256, 74752, stream>>>(QKVb, QKVb + 4096, VbT, Ab);

    // output projection (fp32 out)
    k_gemm_bt2<float><<<dim3(4096 / 128, 2048 / 128), 256, 0, stream>>>(Ab, WoT, out, 2048, 4096, 4096);
}

// Round 9
// 368.287 us; speedup vs baseline: 1.3892x; 1.0115x over previous
//
#include <hip/hip_runtime.h>
#include <hip/hip_bf16.h>
#include <stdint.h>

typedef unsigned short u16;
typedef unsigned int u32;
typedef __bf16 bf16x8 __attribute__((ext_vector_type(8)));
typedef float f32x4 __attribute__((ext_vector_type(4)));
typedef float f32x16 __attribute__((ext_vector_type(16)));
typedef u16 u16x8 __attribute__((ext_vector_type(8)));

#define S_LEN 2048
#define DMODEL 4096
#define NHEADS 32
#define NKVH 8
#define DHEAD 128
#define LDQK 6144   // row stride of fused QKV activation buffer

__device__ __forceinline__ float bf2f(u16 x) {
    union { u32 i; float f; } u; u.i = ((u32)x) << 16; return u.f;
}
__device__ __forceinline__ u16 f2bf(float f) {
    union { float f; u32 i; } u; u.f = f;
    u32 x = u.i;
    return (u16)((x + 0x7fffu + ((x >> 16) & 1u)) >> 16);
}
__device__ __forceinline__ bf16x8 ld_bf8(const void* p) {
    int4 v = *(const int4*)p;
    return __builtin_bit_cast(bf16x8, v);
}

// ---------------- fp32 -> bf16 elementwise ----------------
__global__ void k_cvt(const float* __restrict__ in, u16* __restrict__ out, int n8) {
    int i = blockIdx.x * 256 + threadIdx.x;
    if (i >= n8) return;
    const float4* p = (const float4*)in + (size_t)i * 2;
    float4 a = p[0], b = p[1];
    u16x8 o;
    o[0]=f2bf(a.x); o[1]=f2bf(a.y); o[2]=f2bf(a.z); o[3]=f2bf(a.w);
    o[4]=f2bf(b.x); o[5]=f2bf(b.y); o[6]=f2bf(b.z); o[7]=f2bf(b.w);
    *((u16x8*)out + i) = o;
}

// ---------------- transpose (+convert) to bf16: in[R][C] (ldin) -> out[C][R] ----------------
template<typename TIN>
__global__ void k_transpose_bf16(const TIN* __restrict__ in, u16* __restrict__ out,
                                 int R, int C, int ldin) {
    __shared__ u16 tile[32][33];
    int c0 = blockIdx.x * 32, r0 = blockIdx.y * 32;
    int tx = threadIdx.x & 31, ty = threadIdx.x >> 5;
    #pragma unroll
    for (int i = 0; i < 4; i++) {
        int r = ty + i * 8;
        TIN v = in[(size_t)(r0 + r) * ldin + c0 + tx];
        if constexpr (sizeof(TIN) == 4) tile[r][tx] = f2bf((float)v);
        else tile[r][tx] = (u16)v;
    }
    __syncthreads();
    #pragma unroll
    for (int i = 0; i < 4; i++) {
        int r = ty + i * 8;
        out[(size_t)(c0 + r) * R + r0 + tx] = tile[tx][r];
    }
}

// ---------------- RoPE in place on [S][nh*128] bf16 (row stride ld) ----------------
__global__ void k_rope(u16* __restrict__ X, const float* __restrict__ cosT,
                       const float* __restrict__ sinT, int nh, int ld) {
    int idx = blockIdx.x * 256 + threadIdx.x;
    int d = idx & 63;
    int h = (idx >> 6) % nh;
    int s = idx / (64 * nh);
    u16* p = X + (size_t)s * ld + h * DHEAD;
    float x1 = bf2f(p[d]), x2 = bf2f(p[d + 64]);
    float c1 = cosT[s * DHEAD + d],      s1 = sinT[s * DHEAD + d];
    float c2 = cosT[s * DHEAD + d + 64], s2 = sinT[s * DHEAD + d + 64];
    p[d]      = f2bf(x1 * c1 - x2 * s1);
    p[d + 64] = f2bf(x2 * c2 + x1 * s2);
}

typedef const __attribute__((address_space(1))) u32 GBUF;
typedef __attribute__((address_space(3))) u32 LBUF;

// ---------------- m97-structure 128x128 GEMM, BK=64, swizzled LDS (R7-verified) ----
template<typename OUT_T>
__global__ __launch_bounds__(256)
void k_gemm_bt2(const u16* __restrict__ A, const u16* __restrict__ Bt,
                OUT_T* __restrict__ C, int M, int N, int K) {
    __shared__ __align__(16) u16 As[128 * 64];
    __shared__ __align__(16) u16 Bs[128 * 64];
    const int m0 = blockIdx.y * 128, n0 = blockIdx.x * 128;
    const int tid = threadIdx.x, lane = tid & 63, wid = tid >> 6;
    const int wr = wid >> 1, wc = wid & 1;
    const int g = lane >> 4, lr = lane & 15;

    const u16* sA[4]; const u16* sB[4]; u32 dste[4];
    #pragma unroll
    for (int j = 0; j < 4; j++) {
        int c = j * 256 + tid;
        int row = c >> 3;
        int colsw = (c & 7) ^ (row & 7);
        sA[j] = A  + (size_t)(m0 + row) * K + colsw * 8;
        sB[j] = Bt + (size_t)(n0 + row) * K + colsw * 8;
        dste[j] = (u32)c * 8;
    }
    auto rdoff = [&](int row, int kk) -> u32 {
        return (u32)(row * 128 + ((((kk << 2) + g) ^ (row & 7)) << 4));
    };

    f32x4 acc[4][4] = {};

    for (int k0 = 0; k0 < K; k0 += 64) {
        __syncthreads();
        #pragma unroll
        for (int j = 0; j < 4; j++)
            __builtin_amdgcn_global_load_lds((GBUF*)(sA[j] + k0), (LBUF*)(As + dste[j]), 16, 0, 0);
        #pragma unroll
        for (int j = 0; j < 4; j++)
            __builtin_amdgcn_global_load_lds((GBUF*)(sB[j] + k0), (LBUF*)(Bs + dste[j]), 16, 0, 0);
        __syncthreads();

        bf16x8 af[4][2], bfv[4][2];
        #pragma unroll
        for (int i = 0; i < 4; i++)
            #pragma unroll
            for (int kk = 0; kk < 2; kk++)
                af[i][kk] = ld_bf8((const char*)As + rdoff(wr * 64 + i * 16 + lr, kk));
        #pragma unroll
        for (int n = 0; n < 4; n++)
            #pragma unroll
            for (int kk = 0; kk < 2; kk++)
                bfv[n][kk] = ld_bf8((const char*)Bs + rdoff(wc * 64 + n * 16 + lr, kk));
        #pragma unroll
        for (int i = 0; i < 4; i++)
            #pragma unroll
            for (int n = 0; n < 4; n++)
                #pragma unroll
                for (int kk = 0; kk < 2; kk++)
                    acc[i][n] = __builtin_amdgcn_mfma_f32_16x16x32_bf16(
                        af[i][kk], bfv[n][kk], acc[i][n], 0, 0, 0);
    }
    #pragma unroll
    for (int i = 0; i < 4; i++)
        #pragma unroll
        for (int n = 0; n < 4; n++)
            #pragma unroll
            for (int r = 0; r < 4; r++) {
                int row = m0 + wr * 64 + i * 16 + g * 4 + r;
                int col = n0 + wc * 64 + n * 16 + lr;
                float v = acc[i][n][r];
                if constexpr (sizeof(OUT_T) == 2) C[(size_t)row * N + col] = f2bf(v);
                else                              C[(size_t)row * N + col] = v;
            }
}

// ---------------- attention v3: swapped-QK 32x32 MFMA, in-register softmax ----------------
// R9 fix: diag gate was `64i+63 > q0w+31`, missing the aligned case
// 64i+32 == q0w (waves 1,3) where s1 needs masking -> upper-triangle leak.
// Correct gate: mask whenever max kg (=64i+63) > min qg (=q0w); per-lane
// compares inside are exact, so the gate is safe-side only.
__global__ __launch_bounds__(256, 2)
void k_attn3(const u16* __restrict__ Qb, const u16* __restrict__ Kb,
             const u16* __restrict__ VbT, u16* __restrict__ Ab) {
    extern __shared__ __align__(16) char smem[];

    const int bid = blockIdx.x;
    const int idx = bid & 255;
    int t = idx & 7; if (bid >> 8) t = 15 - t;
    const int h = idx >> 3, hk = h >> 2;
    const int tid = threadIdx.x, lane = tid & 63, wid = tid >> 6;
    const int ql = lane & 31, hi = lane >> 5;
    const float scale = 0.08838834764831845f;  // 1/sqrt(128)
    const int NIT = 2 * t + 2;
    const int q0w = 128 * t + 32 * wid;
    const int qg = q0w + ql;

    const int krow_l = lane >> 4, kc16 = lane & 15;
    const int vrow_l = lane >> 3, vc8  = lane & 7;

    auto stage = [&](int buf, int k0) {
        u16* KsD = (u16*)smem + buf * 8192;
        u16* VtD = (u16*)(smem + 32768) + buf * 8192;
        #pragma unroll
        for (int j = 0; j < 4; j++) {
            int rowt = wid * 16 + j * 4 + krow_l;
            int c16  = kc16 ^ (rowt & 7);
            __builtin_amdgcn_global_load_lds(
                (GBUF*)(Kb + (size_t)(k0 + rowt) * LDQK + hk * DHEAD + c16 * 8),
                (LBUF*)(KsD + (wid * 16 + j * 4) * 128), 16, 0, 0);
        }
        #pragma unroll
        for (int j = 0; j < 4; j++) {
            int rowt = wid * 32 + j * 8 + vrow_l;
            int c8   = vc8 ^ (rowt & 7);
            __builtin_amdgcn_global_load_lds(
                (GBUF*)(VbT + (size_t)(hk * DHEAD + rowt) * S_LEN + k0 + c8 * 8),
                (LBUF*)(VtD + (wid * 32 + j * 8) * 64), 16, 0, 0);
        }
    };

    // Q fragments (B-operand of swapped QK): lane ql -> q-row q0w+ql, 8 d-slices
    bf16x8 qf[8];
    {
        const u16* qrow = Qb + (size_t)qg * LDQK + h * DHEAD;
        #pragma unroll
        for (int dc = 0; dc < 8; dc++)
            qf[dc] = ld_bf8(qrow + dc * 16 + hi * 8);
    }

    f32x16 acc[4] = {};
    float m = -1e30f, lsum = 0.f;
    const int imax = 2 * t + (wid >> 1);   // waves 0,1 idle on the final iter

    stage(0, 0);
    asm volatile("s_waitcnt vmcnt(0)" ::: "memory");
    __builtin_amdgcn_s_barrier();

    for (int i = 0; i < NIT; i++) {
        if (i + 1 < NIT) stage((i + 1) & 1, (i + 1) * 64);

        if (i <= imax) {
            const char* KsB = smem + (i & 1) * 16384;
            const char* VtB = smem + 32768 + (i & 1) * 16384;

            // ---- QK^T swapped: S[k][q], two 32-kv groups ----
            f32x16 s0 = {}, s1 = {};
            __builtin_amdgcn_s_setprio(1);
            #pragma unroll
            for (int dc = 0; dc < 8; dc++) {
                int r0 = ql, r1 = 32 + ql;
                bf16x8 kf0 = ld_bf8(KsB + r0 * 256 + (((2 * dc + hi) ^ (r0 & 7)) << 4));
                bf16x8 kf1 = ld_bf8(KsB + r1 * 256 + (((2 * dc + hi) ^ (r1 & 7)) << 4));
                s0 = __builtin_amdgcn_mfma_f32_32x32x16_bf16(kf0, qf[dc], s0, 0, 0, 0);
                s1 = __builtin_amdgcn_mfma_f32_32x32x16_bf16(kf1, qf[dc], s1, 0, 0, 0);
            }
            __builtin_amdgcn_s_setprio(0);

            // ---- scale + causal mask ----
            float p[2][16];
            bool diag = (64 * i + 63 > q0w);        // R9 FIX: mask iff max kg > min qg
            #pragma unroll
            for (int r = 0; r < 16; r++) {
                int kloc = (r & 3) + 8 * (r >> 2) + 4 * hi;
                float v0 = s0[r] * scale, v1 = s1[r] * scale;
                if (diag) {
                    int kg = 64 * i + kloc;
                    if (kg > qg) v0 = -1e30f;
                    if (kg + 32 > qg) v1 = -1e30f;
                }
                p[0][r] = v0; p[1][r] = v1;
            }

            // ---- in-register online softmax (one q-row per lane) ----
            float mx = p[0][0];
            #pragma unroll
            for (int z = 1; z < 16; z++) mx = fmaxf(mx, p[0][z]);
            #pragma unroll
            for (int z = 0; z < 16; z++) mx = fmaxf(mx, p[1][z]);
            mx = fmaxf(mx, __shfl_xor(mx, 32, 64));
            bool sk = (mx <= m + 8.0f);             // defer-max (T13)
            float mn = sk ? m : mx;
            float corr = sk ? 1.0f : __expf(m - mn);
            m = mn;
            float ts = 0.f;
            #pragma unroll
            for (int g2 = 0; g2 < 2; g2++)
                #pragma unroll
                for (int z = 0; z < 16; z++) {
                    float e = __expf(p[g2][z] - mn);
                    p[g2][z] = e;
                    ts += e;
                }
            ts += __shfl_xor(ts, 32, 64);
            lsum = lsum * corr + ts;
            if (!__all(sk)) {
                float cq[16];
                #pragma unroll
                for (int r = 0; r < 16; r++)
                    cq[r] = __shfl(corr, (r & 3) + 8 * (r >> 2) + 4 * hi, 64);
                #pragma unroll
                for (int db = 0; db < 4; db++)
                    #pragma unroll
                    for (int r = 0; r < 16; r++) acc[db][r] *= cq[r];
            }

            // ---- pack P -> PV A-fragments (no LDS) ----
            bf16x8 pf[4];
            #pragma unroll
            for (int g2 = 0; g2 < 2; g2++) {
                u32 u[8], sw[8];
                #pragma unroll
                for (int z = 0; z < 8; z++)
                    u[z] = (u32)f2bf(p[g2][2 * z]) | ((u32)f2bf(p[g2][2 * z + 1]) << 16);
                #pragma unroll
                for (int z = 0; z < 8; z++) sw[z] = __shfl_xor(u[z], 32, 64);
                #pragma unroll
                for (int ksl = 0; ksl < 2; ksl++) {
                    int4 w4;
                    if (hi) w4 = make_int4(sw[4 * ksl + 2], sw[4 * ksl + 3],
                                           u[4 * ksl + 2],  u[4 * ksl + 3]);
                    else    w4 = make_int4(u[4 * ksl],      u[4 * ksl + 1],
                                           sw[4 * ksl],     sw[4 * ksl + 1]);
                    pf[2 * g2 + ksl] = __builtin_bit_cast(bf16x8, w4);
                }
            }

            // ---- PV: acc[db] += P(32q x 64k) * V(64k x 32d) ----
            __builtin_amdgcn_s_setprio(1);
            #pragma unroll
            for (int db = 0; db < 4; db++) {
                int row = 32 * db + ql;
                #pragma unroll
                for (int ks = 0; ks < 4; ks++) {
                    bf16x8 vf = ld_bf8(VtB + row * 128 + (((2 * ks + hi) ^ (row & 7)) << 4));
                    acc[db] = __builtin_amdgcn_mfma_f32_32x32x16_bf16(pf[ks], vf, acc[db], 0, 0, 0);
                }
            }
            __builtin_amdgcn_s_setprio(0);
        }

        asm volatile("s_waitcnt lgkmcnt(0)" ::: "memory");
        __builtin_amdgcn_sched_barrier(0);
        asm volatile("s_waitcnt vmcnt(0)" ::: "memory");
        __builtin_amdgcn_s_barrier();
    }

    // ---- epilogue: divide by lsum (per q-row, fetched via shfl) and store ----
    float rinv[16];
    #pragma unroll
    for (int r = 0; r < 16; r++)
        rinv[r] = 1.0f / __shfl(lsum, (r & 3) + 8 * (r >> 2) + 4 * hi, 64);
    #pragma unroll
    for (int db = 0; db < 4; db++)
        #pragma unroll
        for (int r = 0; r < 16; r++) {
            int crow = (r & 3) + 8 * (r >> 2) + 4 * hi;
            Ab[(size_t)(q0w + crow) * DMODEL + h * DHEAD + db * 32 + ql]
                = f2bf(acc[db][r] * rinv[r]);
        }
}

extern "C" void kernel_launch(void* const* d_in, const int* in_sizes, int n_in,
                              void* d_out, int out_size, void* d_ws, size_t ws_size,
                              hipStream_t stream) {
    const float* hidden = (const float*)d_in[0];
    const float* cosT   = (const float*)d_in[1];
    const float* sinT   = (const float*)d_in[2];
    // d_in[3] attention_mask: known causal, implemented directly
    const float* Wq = (const float*)d_in[4];
    const float* Wk = (const float*)d_in[5];
    const float* Wv = (const float*)d_in[6];
    const float* Wo = (const float*)d_in[7];
    float* out = (float*)d_out;
    char* ws = (char*)d_ws;

    // workspace (peak 120 MB):
    //   [0,16)    Xbf [2048][4096] bf16; later reused as Ab
    //   [16,64)   WqkvT [6144][4096] bf16 (dead after QKV GEMM); VbT aliases head
    //   [64,96)   WoT [4096][4096] bf16
    //   [96,120)  QKVb [2048][6144] bf16
    u16* Xbf   = (u16*)ws;
    u16* WqkvT = (u16*)(ws + (16u << 20));
    u16* VbT   = (u16*)(ws + (16u << 20));          // alias: valid after QKV GEMM
    u16* WoT   = (u16*)(ws + (64u << 20));
    u16* QKVb  = (u16*)(ws + (96u << 20));
    u16* Ab    = Xbf;

    k_cvt<<<dim3((S_LEN * DMODEL / 8) / 256), 256, 0, stream>>>(hidden, Xbf, S_LEN * DMODEL / 8);
    k_transpose_bf16<float><<<dim3(4096 / 32, 4096 / 32), 256, 0, stream>>>(Wq, WqkvT, 4096, 4096, 4096);
    k_transpose_bf16<float><<<dim3(1024 / 32, 4096 / 32), 256, 0, stream>>>(Wk, WqkvT + (size_t)4096 * 4096, 4096, 1024, 1024);
    k_transpose_bf16<float><<<dim3(1024 / 32, 4096 / 32), 256, 0, stream>>>(Wv, WqkvT + (size_t)5120 * 4096, 4096, 1024, 1024);
    k_transpose_bf16<float><<<dim3(4096 / 32, 4096 / 32), 256, 0, stream>>>(Wo, WoT, 4096, 4096, 4096);

    // fused QKV projection: [2048][4096] x [6144][4096]^T -> [2048][6144]
    k_gemm_bt2<u16><<<dim3(6144 / 128, 2048 / 128), 256, 0, stream>>>(Xbf, WqkvT, QKVb, 2048, 6144, 4096);

    // RoPE on Q (cols 0..4095) and K (cols 4096..5119)
    k_rope<<<(2048 * 32 * 64) / 256, 256, 0, stream>>>(QKVb, cosT, sinT, 32, LDQK);
    k_rope<<<(2048 * 8 * 64) / 256, 256, 0, stream>>>(QKVb + 4096, cosT, sinT, 8, LDQK);

    // V^T (cols 5120..6143 of QKVb) -> VbT [1024][2048]
    k_transpose_bf16<u16><<<dim3(1024 / 32, 2048 / 32), 256, 0, stream>>>(QKVb + 5120, VbT, 2048, 1024, LDQK);

    // attention v3: 512 blocks (t anti-correlated across halves), 64 KB dynamic LDS
    hipFuncSetAttribute((const void*)k_attn3, hipFuncAttributeMaxDynamicSharedMemorySize, 65536);
    k_attn3<<<dim3(512), 256, 65536, stream>>>(QKVb, QKVb + 4096, VbT, Ab);

    // output projection (fp32 out)
    k_gemm_bt2<float><<<dim3(4096 / 128, 2048 / 128), 256, 0, stream>>>(Ab, WoT, out, 2048, 4096, 4096);
}

// Round 10
// 362.814 us; speedup vs baseline: 1.4102x; 1.0151x over previous
//
#include <hip/hip_runtime.h>
#include <hip/hip_bf16.h>
#include <stdint.h>

typedef unsigned short u16;
typedef unsigned int u32;
typedef __bf16 bf16x8 __attribute__((ext_vector_type(8)));
typedef float f32x4 __attribute__((ext_vector_type(4)));
typedef float f32x16 __attribute__((ext_vector_type(16)));
typedef u16 u16x8 __attribute__((ext_vector_type(8)));

#define S_LEN 2048
#define DMODEL 4096
#define NHEADS 32
#define NKVH 8
#define DHEAD 128
#define LDQK 6144   // row stride of fused QKV activation buffer

__device__ __forceinline__ float bf2f(u16 x) {
    union { u32 i; float f; } u; u.i = ((u32)x) << 16; return u.f;
}
__device__ __forceinline__ u16 f2bf(float f) {
    union { float f; u32 i; } u; u.f = f;
    u32 x = u.i;
    return (u16)((x + 0x7fffu + ((x >> 16) & 1u)) >> 16);
}
__device__ __forceinline__ bf16x8 ld_bf8(const void* p) {
    int4 v = *(const int4*)p;
    return __builtin_bit_cast(bf16x8, v);
}

// ---------------- fp32 -> bf16 elementwise ----------------
__global__ void k_cvt(const float* __restrict__ in, u16* __restrict__ out, int n8) {
    int i = blockIdx.x * 256 + threadIdx.x;
    if (i >= n8) return;
    const float4* p = (const float4*)in + (size_t)i * 2;
    float4 a = p[0], b = p[1];
    u16x8 o;
    o[0]=f2bf(a.x); o[1]=f2bf(a.y); o[2]=f2bf(a.z); o[3]=f2bf(a.w);
    o[4]=f2bf(b.x); o[5]=f2bf(b.y); o[6]=f2bf(b.z); o[7]=f2bf(b.w);
    *((u16x8*)out + i) = o;
}

// ---------------- fast weight transpose: fp32 in[R][C] -> bf16 out[C][R] ----------------
// 64x64 tiles, 256 threads. Phase 1: float4 reads (256B/row segment), convert,
// row-major LDS store (stride 68 u16 = 136B). Phase 2: per out-row chunk, 8
// scalar column-gathers (banks spread by stride-17-word rows), pack u16x8,
// 16B store with 8 lanes/row -> 128B coalesced write segments.
__global__ __launch_bounds__(256)
void k_transpose_w(const float* __restrict__ in, u16* __restrict__ out, int R, int C) {
    __shared__ u16 tile[64][68];
    const int c0 = blockIdx.x * 64, r0 = blockIdx.y * 64;
    const int tid = threadIdx.x, lane = tid & 63, wid = tid >> 6;

    const int ch = lane & 15;               // float4 chunk (4 cols)
    const int rr = (lane >> 4) + wid * 4;   // 16 rows per pass
    #pragma unroll
    for (int it = 0; it < 4; it++) {
        int r = rr + it * 16;
        float4 v = *(const float4*)(in + (size_t)(r0 + r) * C + c0 + ch * 4);
        u16* t = &tile[r][ch * 4];
        t[0] = f2bf(v.x); t[1] = f2bf(v.y); t[2] = f2bf(v.z); t[3] = f2bf(v.w);
    }
    __syncthreads();
    const int k8 = lane & 7;                // 8 r-chunks of 8
    const int cb = (lane >> 3) + wid * 8;   // 32 out-rows per pass
    #pragma unroll
    for (int it = 0; it < 2; it++) {
        int c = cb + it * 32;
        u16x8 o;
        #pragma unroll
        for (int i = 0; i < 8; i++) o[i] = tile[k8 * 8 + i][c];
        *(u16x8*)(out + (size_t)(c0 + c) * R + r0 + k8 * 8) = o;
    }
}

// ---------------- transpose (+convert) to bf16: in[R][C] (ldin) -> out[C][R] ----------------
// (kept for the small u16 V^T transpose only)
template<typename TIN>
__global__ void k_transpose_bf16(const TIN* __restrict__ in, u16* __restrict__ out,
                                 int R, int C, int ldin) {
    __shared__ u16 tile[32][33];
    int c0 = blockIdx.x * 32, r0 = blockIdx.y * 32;
    int tx = threadIdx.x & 31, ty = threadIdx.x >> 5;
    #pragma unroll
    for (int i = 0; i < 4; i++) {
        int r = ty + i * 8;
        TIN v = in[(size_t)(r0 + r) * ldin + c0 + tx];
        if constexpr (sizeof(TIN) == 4) tile[r][tx] = f2bf((float)v);
        else tile[r][tx] = (u16)v;
    }
    __syncthreads();
    #pragma unroll
    for (int i = 0; i < 4; i++) {
        int r = ty + i * 8;
        out[(size_t)(c0 + r) * R + r0 + tx] = tile[tx][r];
    }
}

// ---------------- RoPE in place on [S][nh*128] bf16 (row stride ld) ----------------
__global__ void k_rope(u16* __restrict__ X, const float* __restrict__ cosT,
                       const float* __restrict__ sinT, int nh, int ld) {
    int idx = blockIdx.x * 256 + threadIdx.x;
    int d = idx & 63;
    int h = (idx >> 6) % nh;
    int s = idx / (64 * nh);
    u16* p = X + (size_t)s * ld + h * DHEAD;
    float x1 = bf2f(p[d]), x2 = bf2f(p[d + 64]);
    float c1 = cosT[s * DHEAD + d],      s1 = sinT[s * DHEAD + d];
    float c2 = cosT[s * DHEAD + d + 64], s2 = sinT[s * DHEAD + d + 64];
    p[d]      = f2bf(x1 * c1 - x2 * s1);
    p[d + 64] = f2bf(x2 * c2 + x1 * s2);
}

typedef const __attribute__((address_space(1))) u32 GBUF;
typedef __attribute__((address_space(3))) u32 LBUF;

// ---------------- m97-structure 128x128 GEMM, BK=64, swizzled LDS (R7-verified) ----
template<typename OUT_T>
__global__ __launch_bounds__(256)
void k_gemm_bt2(const u16* __restrict__ A, const u16* __restrict__ Bt,
                OUT_T* __restrict__ C, int M, int N, int K) {
    __shared__ __align__(16) u16 As[128 * 64];
    __shared__ __align__(16) u16 Bs[128 * 64];
    const int m0 = blockIdx.y * 128, n0 = blockIdx.x * 128;
    const int tid = threadIdx.x, lane = tid & 63, wid = tid >> 6;
    const int wr = wid >> 1, wc = wid & 1;
    const int g = lane >> 4, lr = lane & 15;

    const u16* sA[4]; const u16* sB[4]; u32 dste[4];
    #pragma unroll
    for (int j = 0; j < 4; j++) {
        int c = j * 256 + tid;
        int row = c >> 3;
        int colsw = (c & 7) ^ (row & 7);
        sA[j] = A  + (size_t)(m0 + row) * K + colsw * 8;
        sB[j] = Bt + (size_t)(n0 + row) * K + colsw * 8;
        dste[j] = (u32)c * 8;
    }
    auto rdoff = [&](int row, int kk) -> u32 {
        return (u32)(row * 128 + ((((kk << 2) + g) ^ (row & 7)) << 4));
    };

    f32x4 acc[4][4] = {};

    for (int k0 = 0; k0 < K; k0 += 64) {
        __syncthreads();
        #pragma unroll
        for (int j = 0; j < 4; j++)
            __builtin_amdgcn_global_load_lds((GBUF*)(sA[j] + k0), (LBUF*)(As + dste[j]), 16, 0, 0);
        #pragma unroll
        for (int j = 0; j < 4; j++)
            __builtin_amdgcn_global_load_lds((GBUF*)(sB[j] + k0), (LBUF*)(Bs + dste[j]), 16, 0, 0);
        __syncthreads();

        bf16x8 af[4][2], bfv[4][2];
        #pragma unroll
        for (int i = 0; i < 4; i++)
            #pragma unroll
            for (int kk = 0; kk < 2; kk++)
                af[i][kk] = ld_bf8((const char*)As + rdoff(wr * 64 + i * 16 + lr, kk));
        #pragma unroll
        for (int n = 0; n < 4; n++)
            #pragma unroll
            for (int kk = 0; kk < 2; kk++)
                bfv[n][kk] = ld_bf8((const char*)Bs + rdoff(wc * 64 + n * 16 + lr, kk));
        #pragma unroll
        for (int i = 0; i < 4; i++)
            #pragma unroll
            for (int n = 0; n < 4; n++)
                #pragma unroll
                for (int kk = 0; kk < 2; kk++)
                    acc[i][n] = __builtin_amdgcn_mfma_f32_16x16x32_bf16(
                        af[i][kk], bfv[n][kk], acc[i][n], 0, 0, 0);
    }
    #pragma unroll
    for (int i = 0; i < 4; i++)
        #pragma unroll
        for (int n = 0; n < 4; n++)
            #pragma unroll
            for (int r = 0; r < 4; r++) {
                int row = m0 + wr * 64 + i * 16 + g * 4 + r;
                int col = n0 + wc * 64 + n * 16 + lr;
                float v = acc[i][n][r];
                if constexpr (sizeof(OUT_T) == 2) C[(size_t)row * N + col] = f2bf(v);
                else                              C[(size_t)row * N + col] = v;
            }
}

// ---------------- attention v3: swapped-QK 32x32 MFMA, in-register softmax (R9-verified) ----
__global__ __launch_bounds__(256, 2)
void k_attn3(const u16* __restrict__ Qb, const u16* __restrict__ Kb,
             const u16* __restrict__ VbT, u16* __restrict__ Ab) {
    extern __shared__ __align__(16) char smem[];

    const int bid = blockIdx.x;
    const int idx = bid & 255;
    int t = idx & 7; if (bid >> 8) t = 15 - t;
    const int h = idx >> 3, hk = h >> 2;
    const int tid = threadIdx.x, lane = tid & 63, wid = tid >> 6;
    const int ql = lane & 31, hi = lane >> 5;
    const float scale = 0.08838834764831845f;  // 1/sqrt(128)
    const int NIT = 2 * t + 2;
    const int q0w = 128 * t + 32 * wid;
    const int qg = q0w + ql;

    const int krow_l = lane >> 4, kc16 = lane & 15;
    const int vrow_l = lane >> 3, vc8  = lane & 7;

    auto stage = [&](int buf, int k0) {
        u16* KsD = (u16*)smem + buf * 8192;
        u16* VtD = (u16*)(smem + 32768) + buf * 8192;
        #pragma unroll
        for (int j = 0; j < 4; j++) {
            int rowt = wid * 16 + j * 4 + krow_l;
            int c16  = kc16 ^ (rowt & 7);
            __builtin_amdgcn_global_load_lds(
                (GBUF*)(Kb + (size_t)(k0 + rowt) * LDQK + hk * DHEAD + c16 * 8),
                (LBUF*)(KsD + (wid * 16 + j * 4) * 128), 16, 0, 0);
        }
        #pragma unroll
        for (int j = 0; j < 4; j++) {
            int rowt = wid * 32 + j * 8 + vrow_l;
            int c8   = vc8 ^ (rowt & 7);
            __builtin_amdgcn_global_load_lds(
                (GBUF*)(VbT + (size_t)(hk * DHEAD + rowt) * S_LEN + k0 + c8 * 8),
                (LBUF*)(VtD + (wid * 32 + j * 8) * 64), 16, 0, 0);
        }
    };

    bf16x8 qf[8];
    {
        const u16* qrow = Qb + (size_t)qg * LDQK + h * DHEAD;
        #pragma unroll
        for (int dc = 0; dc < 8; dc++)
            qf[dc] = ld_bf8(qrow + dc * 16 + hi * 8);
    }

    f32x16 acc[4] = {};
    float m = -1e30f, lsum = 0.f;
    const int imax = 2 * t + (wid >> 1);

    stage(0, 0);
    asm volatile("s_waitcnt vmcnt(0)" ::: "memory");
    __builtin_amdgcn_s_barrier();

    for (int i = 0; i < NIT; i++) {
        if (i + 1 < NIT) stage((i + 1) & 1, (i + 1) * 64);

        if (i <= imax) {
            const char* KsB = smem + (i & 1) * 16384;
            const char* VtB = smem + 32768 + (i & 1) * 16384;

            f32x16 s0 = {}, s1 = {};
            __builtin_amdgcn_s_setprio(1);
            #pragma unroll
            for (int dc = 0; dc < 8; dc++) {
                int r0 = ql, r1 = 32 + ql;
                bf16x8 kf0 = ld_bf8(KsB + r0 * 256 + (((2 * dc + hi) ^ (r0 & 7)) << 4));
                bf16x8 kf1 = ld_bf8(KsB + r1 * 256 + (((2 * dc + hi) ^ (r1 & 7)) << 4));
                s0 = __builtin_amdgcn_mfma_f32_32x32x16_bf16(kf0, qf[dc], s0, 0, 0, 0);
                s1 = __builtin_amdgcn_mfma_f32_32x32x16_bf16(kf1, qf[dc], s1, 0, 0, 0);
            }
            __builtin_amdgcn_s_setprio(0);

            float p[2][16];
            bool diag = (64 * i + 63 > q0w);
            #pragma unroll
            for (int r = 0; r < 16; r++) {
                int kloc = (r & 3) + 8 * (r >> 2) + 4 * hi;
                float v0 = s0[r] * scale, v1 = s1[r] * scale;
                if (diag) {
                    int kg = 64 * i + kloc;
                    if (kg > qg) v0 = -1e30f;
                    if (kg + 32 > qg) v1 = -1e30f;
                }
                p[0][r] = v0; p[1][r] = v1;
            }

            float mx = p[0][0];
            #pragma unroll
            for (int z = 1; z < 16; z++) mx = fmaxf(mx, p[0][z]);
            #pragma unroll
            for (int z = 0; z < 16; z++) mx = fmaxf(mx, p[1][z]);
            mx = fmaxf(mx, __shfl_xor(mx, 32, 64));
            bool sk = (mx <= m + 8.0f);
            float mn = sk ? m : mx;
            float corr = sk ? 1.0f : __expf(m - mn);
            m = mn;
            float ts = 0.f;
            #pragma unroll
            for (int g2 = 0; g2 < 2; g2++)
                #pragma unroll
                for (int z = 0; z < 16; z++) {
                    float e = __expf(p[g2][z] - mn);
                    p[g2][z] = e;
                    ts += e;
                }
            ts += __shfl_xor(ts, 32, 64);
            lsum = lsum * corr + ts;
            if (!__all(sk)) {
                float cq[16];
                #pragma unroll
                for (int r = 0; r < 16; r++)
                    cq[r] = __shfl(corr, (r & 3) + 8 * (r >> 2) + 4 * hi, 64);
                #pragma unroll
                for (int db = 0; db < 4; db++)
                    #pragma unroll
                    for (int r = 0; r < 16; r++) acc[db][r] *= cq[r];
            }

            bf16x8 pf[4];
            #pragma unroll
            for (int g2 = 0; g2 < 2; g2++) {
                u32 u[8], sw[8];
                #pragma unroll
                for (int z = 0; z < 8; z++)
                    u[z] = (u32)f2bf(p[g2][2 * z]) | ((u32)f2bf(p[g2][2 * z + 1]) << 16);
                #pragma unroll
                for (int z = 0; z < 8; z++) sw[z] = __shfl_xor(u[z], 32, 64);
                #pragma unroll
                for (int ksl = 0; ksl < 2; ksl++) {
                    int4 w4;
                    if (hi) w4 = make_int4(sw[4 * ksl + 2], sw[4 * ksl + 3],
                                           u[4 * ksl + 2],  u[4 * ksl + 3]);
                    else    w4 = make_int4(u[4 * ksl],      u[4 * ksl + 1],
                                           sw[4 * ksl],     sw[4 * ksl + 1]);
                    pf[2 * g2 + ksl] = __builtin_bit_cast(bf16x8, w4);
                }
            }

            __builtin_amdgcn_s_setprio(1);
            #pragma unroll
            for (int db = 0; db < 4; db++) {
                int row = 32 * db + ql;
                #pragma unroll
                for (int ks = 0; ks < 4; ks++) {
                    bf16x8 vf = ld_bf8(VtB + row * 128 + (((2 * ks + hi) ^ (row & 7)) << 4));
                    acc[db] = __builtin_amdgcn_mfma_f32_32x32x16_bf16(pf[ks], vf, acc[db], 0, 0, 0);
                }
            }
            __builtin_amdgcn_s_setprio(0);
        }

        asm volatile("s_waitcnt lgkmcnt(0)" ::: "memory");
        __builtin_amdgcn_sched_barrier(0);
        asm volatile("s_waitcnt vmcnt(0)" ::: "memory");
        __builtin_amdgcn_s_barrier();
    }

    float rinv[16];
    #pragma unroll
    for (int r = 0; r < 16; r++)
        rinv[r] = 1.0f / __shfl(lsum, (r & 3) + 8 * (r >> 2) + 4 * hi, 64);
    #pragma unroll
    for (int db = 0; db < 4; db++)
        #pragma unroll
        for (int r = 0; r < 16; r++) {
            int crow = (r & 3) + 8 * (r >> 2) + 4 * hi;
            Ab[(size_t)(q0w + crow) * DMODEL + h * DHEAD + db * 32 + ql]
                = f2bf(acc[db][r] * rinv[r]);
        }
}

extern "C" void kernel_launch(void* const* d_in, const int* in_sizes, int n_in,
                              void* d_out, int out_size, void* d_ws, size_t ws_size,
                              hipStream_t stream) {
    const float* hidden = (const float*)d_in[0];
    const float* cosT   = (const float*)d_in[1];
    const float* sinT   = (const float*)d_in[2];
    // d_in[3] attention_mask: known causal, implemented directly
    const float* Wq = (const float*)d_in[4];
    const float* Wk = (const float*)d_in[5];
    const float* Wv = (const float*)d_in[6];
    const float* Wo = (const float*)d_in[7];
    float* out = (float*)d_out;
    char* ws = (char*)d_ws;

    // workspace (peak 120 MB):
    //   [0,16)    Xbf [2048][4096] bf16; later reused as Ab
    //   [16,64)   WqkvT [6144][4096] bf16 (dead after QKV GEMM); VbT aliases head
    //   [64,96)   WoT [4096][4096] bf16
    //   [96,120)  QKVb [2048][6144] bf16
    u16* Xbf   = (u16*)ws;
    u16* WqkvT = (u16*)(ws + (16u << 20));
    u16* VbT   = (u16*)(ws + (16u << 20));          // alias: valid after QKV GEMM
    u16* WoT   = (u16*)(ws + (64u << 20));
    u16* QKVb  = (u16*)(ws + (96u << 20));
    u16* Ab    = Xbf;

    k_cvt<<<dim3((S_LEN * DMODEL / 8) / 256), 256, 0, stream>>>(hidden, Xbf, S_LEN * DMODEL / 8);
    k_transpose_w<<<dim3(4096 / 64, 4096 / 64), 256, 0, stream>>>(Wq, WqkvT, 4096, 4096);
    k_transpose_w<<<dim3(1024 / 64, 4096 / 64), 256, 0, stream>>>(Wk, WqkvT + (size_t)4096 * 4096, 4096, 1024);
    k_transpose_w<<<dim3(1024 / 64, 4096 / 64), 256, 0, stream>>>(Wv, WqkvT + (size_t)5120 * 4096, 4096, 1024);
    k_transpose_w<<<dim3(4096 / 64, 4096 / 64), 256, 0, stream>>>(Wo, WoT, 4096, 4096);

    // fused QKV projection: [2048][4096] x [6144][4096]^T -> [2048][6144]
    k_gemm_bt2<u16><<<dim3(6144 / 128, 2048 / 128), 256, 0, stream>>>(Xbf, WqkvT, QKVb, 2048, 6144, 4096);

    // RoPE on Q (cols 0..4095) and K (cols 4096..5119)
    k_rope<<<(2048 * 32 * 64) / 256, 256, 0, stream>>>(QKVb, cosT, sinT, 32, LDQK);
    k_rope<<<(2048 * 8 * 64) / 256, 256, 0, stream>>>(QKVb + 4096, cosT, sinT, 8, LDQK);

    // V^T (cols 5120..6143 of QKVb) -> VbT [1024][2048]
    k_transpose_bf16<u16><<<dim3(1024 / 32, 2048 / 32), 256, 0, stream>>>(QKVb + 5120, VbT, 2048, 1024, LDQK);

    // attention v3: 512 blocks (t anti-correlated across halves), 64 KB dynamic LDS
    hipFuncSetAttribute((const void*)k_attn3, hipFuncAttributeMaxDynamicSharedMemorySize, 65536);
    k_attn3<<<dim3(512), 256, 65536, stream>>>(QKVb, QKVb + 4096, VbT, Ab);

    // output projection (fp32 out)
    k_gemm_bt2<float><<<dim3(4096 / 128, 2048 / 128), 256, 0, stream>>>(Ab, WoT, out, 2048, 4096, 4096);
}

// Round 11
// 359.403 us; speedup vs baseline: 1.4235x; 1.0095x over previous
//
#include <hip/hip_runtime.h>
#include <hip/hip_bf16.h>
#include <stdint.h>

typedef unsigned short u16;
typedef unsigned int u32;
typedef __bf16 bf16x8 __attribute__((ext_vector_type(8)));
typedef float f32x4 __attribute__((ext_vector_type(4)));
typedef float f32x16 __attribute__((ext_vector_type(16)));
typedef u16 u16x8 __attribute__((ext_vector_type(8)));

#define S_LEN 2048
#define DMODEL 4096
#define NHEADS 32
#define NKVH 8
#define DHEAD 128
#define LDQK 6144   // row stride of fused QKV activation buffer

__device__ __forceinline__ float bf2f(u16 x) {
    union { u32 i; float f; } u; u.i = ((u32)x) << 16; return u.f;
}
__device__ __forceinline__ u16 f2bf(float f) {
    union { float f; u32 i; } u; u.f = f;
    u32 x = u.i;
    return (u16)((x + 0x7fffu + ((x >> 16) & 1u)) >> 16);
}
__device__ __forceinline__ bf16x8 ld_bf8(const void* p) {
    int4 v = *(const int4*)p;
    return __builtin_bit_cast(bf16x8, v);
}

// ---------------- fp32 -> bf16 elementwise ----------------
__global__ void k_cvt(const float* __restrict__ in, u16* __restrict__ out, int n8) {
    int i = blockIdx.x * 256 + threadIdx.x;
    if (i >= n8) return;
    const float4* p = (const float4*)in + (size_t)i * 2;
    float4 a = p[0], b = p[1];
    u16x8 o;
    o[0]=f2bf(a.x); o[1]=f2bf(a.y); o[2]=f2bf(a.z); o[3]=f2bf(a.w);
    o[4]=f2bf(b.x); o[5]=f2bf(b.y); o[6]=f2bf(b.z); o[7]=f2bf(b.w);
    *((u16x8*)out + i) = o;
}

// ---------------- fast weight transpose: fp32 in[R][C] -> bf16 out[C][R] ----------------
__global__ __launch_bounds__(256)
void k_transpose_w(const float* __restrict__ in, u16* __restrict__ out, int R, int C) {
    __shared__ u16 tile[64][68];
    const int c0 = blockIdx.x * 64, r0 = blockIdx.y * 64;
    const int tid = threadIdx.x, lane = tid & 63, wid = tid >> 6;

    const int ch = lane & 15;
    const int rr = (lane >> 4) + wid * 4;
    #pragma unroll
    for (int it = 0; it < 4; it++) {
        int r = rr + it * 16;
        float4 v = *(const float4*)(in + (size_t)(r0 + r) * C + c0 + ch * 4);
        u16* t = &tile[r][ch * 4];
        t[0] = f2bf(v.x); t[1] = f2bf(v.y); t[2] = f2bf(v.z); t[3] = f2bf(v.w);
    }
    __syncthreads();
    const int k8 = lane & 7;
    const int cb = (lane >> 3) + wid * 8;
    #pragma unroll
    for (int it = 0; it < 2; it++) {
        int c = cb + it * 32;
        u16x8 o;
        #pragma unroll
        for (int i = 0; i < 8; i++) o[i] = tile[k8 * 8 + i][c];
        *(u16x8*)(out + (size_t)(c0 + c) * R + r0 + k8 * 8) = o;
    }
}

// ---------------- transpose u16 (V^T only) ----------------
template<typename TIN>
__global__ void k_transpose_bf16(const TIN* __restrict__ in, u16* __restrict__ out,
                                 int R, int C, int ldin) {
    __shared__ u16 tile[32][33];
    int c0 = blockIdx.x * 32, r0 = blockIdx.y * 32;
    int tx = threadIdx.x & 31, ty = threadIdx.x >> 5;
    #pragma unroll
    for (int i = 0; i < 4; i++) {
        int r = ty + i * 8;
        TIN v = in[(size_t)(r0 + r) * ldin + c0 + tx];
        if constexpr (sizeof(TIN) == 4) tile[r][tx] = f2bf((float)v);
        else tile[r][tx] = (u16)v;
    }
    __syncthreads();
    #pragma unroll
    for (int i = 0; i < 4; i++) {
        int r = ty + i * 8;
        out[(size_t)(c0 + r) * R + r0 + tx] = tile[tx][r];
    }
}

// ---------------- RoPE in place on [S][nh*128] bf16 (row stride ld) ----------------
__global__ void k_rope(u16* __restrict__ X, const float* __restrict__ cosT,
                       const float* __restrict__ sinT, int nh, int ld) {
    int idx = blockIdx.x * 256 + threadIdx.x;
    int d = idx & 63;
    int h = (idx >> 6) % nh;
    int s = idx / (64 * nh);
    u16* p = X + (size_t)s * ld + h * DHEAD;
    float x1 = bf2f(p[d]), x2 = bf2f(p[d + 64]);
    float c1 = cosT[s * DHEAD + d],      s1 = sinT[s * DHEAD + d];
    float c2 = cosT[s * DHEAD + d + 64], s2 = sinT[s * DHEAD + d + 64];
    p[d]      = f2bf(x1 * c1 - x2 * s1);
    p[d + 64] = f2bf(x2 * c2 + x1 * s2);
}

typedef const __attribute__((address_space(1))) u32 GBUF;
typedef __attribute__((address_space(3))) u32 LBUF;

// ---------------- m97-structure 128x128 GEMM, BK=64, swizzled LDS (R7-verified) ----
template<typename OUT_T>
__global__ __launch_bounds__(256)
void k_gemm_bt2(const u16* __restrict__ A, const u16* __restrict__ Bt,
                OUT_T* __restrict__ C, int M, int N, int K) {
    __shared__ __align__(16) u16 As[128 * 64];
    __shared__ __align__(16) u16 Bs[128 * 64];
    const int m0 = blockIdx.y * 128, n0 = blockIdx.x * 128;
    const int tid = threadIdx.x, lane = tid & 63, wid = tid >> 6;
    const int wr = wid >> 1, wc = wid & 1;
    const int g = lane >> 4, lr = lane & 15;

    const u16* sA[4]; const u16* sB[4]; u32 dste[4];
    #pragma unroll
    for (int j = 0; j < 4; j++) {
        int c = j * 256 + tid;
        int row = c >> 3;
        int colsw = (c & 7) ^ (row & 7);
        sA[j] = A  + (size_t)(m0 + row) * K + colsw * 8;
        sB[j] = Bt + (size_t)(n0 + row) * K + colsw * 8;
        dste[j] = (u32)c * 8;
    }
    auto rdoff = [&](int row, int kk) -> u32 {
        return (u32)(row * 128 + ((((kk << 2) + g) ^ (row & 7)) << 4));
    };

    f32x4 acc[4][4] = {};

    for (int k0 = 0; k0 < K; k0 += 64) {
        __syncthreads();
        #pragma unroll
        for (int j = 0; j < 4; j++)
            __builtin_amdgcn_global_load_lds((GBUF*)(sA[j] + k0), (LBUF*)(As + dste[j]), 16, 0, 0);
        #pragma unroll
        for (int j = 0; j < 4; j++)
            __builtin_amdgcn_global_load_lds((GBUF*)(sB[j] + k0), (LBUF*)(Bs + dste[j]), 16, 0, 0);
        __syncthreads();

        bf16x8 af[4][2], bfv[4][2];
        #pragma unroll
        for (int i = 0; i < 4; i++)
            #pragma unroll
            for (int kk = 0; kk < 2; kk++)
                af[i][kk] = ld_bf8((const char*)As + rdoff(wr * 64 + i * 16 + lr, kk));
        #pragma unroll
        for (int n = 0; n < 4; n++)
            #pragma unroll
            for (int kk = 0; kk < 2; kk++)
                bfv[n][kk] = ld_bf8((const char*)Bs + rdoff(wc * 64 + n * 16 + lr, kk));
        #pragma unroll
        for (int i = 0; i < 4; i++)
            #pragma unroll
            for (int n = 0; n < 4; n++)
                #pragma unroll
                for (int kk = 0; kk < 2; kk++)
                    acc[i][n] = __builtin_amdgcn_mfma_f32_16x16x32_bf16(
                        af[i][kk], bfv[n][kk], acc[i][n], 0, 0, 0);
    }
    #pragma unroll
    for (int i = 0; i < 4; i++)
        #pragma unroll
        for (int n = 0; n < 4; n++)
            #pragma unroll
            for (int r = 0; r < 4; r++) {
                int row = m0 + wr * 64 + i * 16 + g * 4 + r;
                int col = n0 + wc * 64 + n * 16 + lr;
                float v = acc[i][n][r];
                if constexpr (sizeof(OUT_T) == 2) C[(size_t)row * N + col] = f2bf(v);
                else                              C[(size_t)row * N + col] = v;
            }
}

// ---------------- attention v4: v3 + register diet (anti-spill) ----------------
// R11 theory: v3 spilled (est. live set 230-260 vs 256 cap). Diet: exp in place
// in s0/s1 (kills p[2][16]); pack via v_cvt_pk_bf16_f32 windowed 4-at-a-time
// (kills u/sw[8], -170 VALU ops/iter); scalar temps for rescale/epilogue
// (kills cq[16]/rinv[16]); tree max + 4-partial exp-sum. Math identical to R9.
__global__ __launch_bounds__(256, 2)
void k_attn3(const u16* __restrict__ Qb, const u16* __restrict__ Kb,
             const u16* __restrict__ VbT, u16* __restrict__ Ab) {
    extern __shared__ __align__(16) char smem[];

    const int bid = blockIdx.x;
    const int idx = bid & 255;
    int t = idx & 7; if (bid >> 8) t = 15 - t;
    const int h = idx >> 3, hk = h >> 2;
    const int tid = threadIdx.x, lane = tid & 63, wid = tid >> 6;
    const int ql = lane & 31, hi = lane >> 5;
    const float scale = 0.08838834764831845f;  // 1/sqrt(128)
    const int NIT = 2 * t + 2;
    const int q0w = 128 * t + 32 * wid;
    const int qg = q0w + ql;

    const int krow_l = lane >> 4, kc16 = lane & 15;
    const int vrow_l = lane >> 3, vc8  = lane & 7;

    auto stage = [&](int buf, int k0) {
        u16* KsD = (u16*)smem + buf * 8192;
        u16* VtD = (u16*)(smem + 32768) + buf * 8192;
        #pragma unroll
        for (int j = 0; j < 4; j++) {
            int rowt = wid * 16 + j * 4 + krow_l;
            int c16  = kc16 ^ (rowt & 7);
            __builtin_amdgcn_global_load_lds(
                (GBUF*)(Kb + (size_t)(k0 + rowt) * LDQK + hk * DHEAD + c16 * 8),
                (LBUF*)(KsD + (wid * 16 + j * 4) * 128), 16, 0, 0);
        }
        #pragma unroll
        for (int j = 0; j < 4; j++) {
            int rowt = wid * 32 + j * 8 + vrow_l;
            int c8   = vc8 ^ (rowt & 7);
            __builtin_amdgcn_global_load_lds(
                (GBUF*)(VbT + (size_t)(hk * DHEAD + rowt) * S_LEN + k0 + c8 * 8),
                (LBUF*)(VtD + (wid * 32 + j * 8) * 64), 16, 0, 0);
        }
    };

    bf16x8 qf[8];
    {
        const u16* qrow = Qb + (size_t)qg * LDQK + h * DHEAD;
        #pragma unroll
        for (int dc = 0; dc < 8; dc++)
            qf[dc] = ld_bf8(qrow + dc * 16 + hi * 8);
    }

    f32x16 acc[4] = {};
    float m = -1e30f, lsum = 0.f;
    const int imax = 2 * t + (wid >> 1);

    stage(0, 0);
    asm volatile("s_waitcnt vmcnt(0)" ::: "memory");
    __builtin_amdgcn_s_barrier();

    for (int i = 0; i < NIT; i++) {
        if (i + 1 < NIT) stage((i + 1) & 1, (i + 1) * 64);

        if (i <= imax) {
            const char* KsB = smem + (i & 1) * 16384;
            const char* VtB = smem + 32768 + (i & 1) * 16384;

            // ---- QK^T swapped: S[k][q], two 32-kv groups ----
            f32x16 s0 = {}, s1 = {};
            __builtin_amdgcn_s_setprio(1);
            #pragma unroll
            for (int dc = 0; dc < 8; dc++) {
                int r0 = ql, r1 = 32 + ql;
                bf16x8 kf0 = ld_bf8(KsB + r0 * 256 + (((2 * dc + hi) ^ (r0 & 7)) << 4));
                bf16x8 kf1 = ld_bf8(KsB + r1 * 256 + (((2 * dc + hi) ^ (r1 & 7)) << 4));
                s0 = __builtin_amdgcn_mfma_f32_32x32x16_bf16(kf0, qf[dc], s0, 0, 0, 0);
                s1 = __builtin_amdgcn_mfma_f32_32x32x16_bf16(kf1, qf[dc], s1, 0, 0, 0);
            }
            __builtin_amdgcn_s_setprio(0);

            // ---- scale + causal mask, in place ----
            bool diag = (64 * i + 63 > q0w);
            #pragma unroll
            for (int r = 0; r < 16; r++) {
                int kloc = (r & 3) + 8 * (r >> 2) + 4 * hi;
                float v0 = s0[r] * scale, v1 = s1[r] * scale;
                if (diag) {
                    int kg = 64 * i + kloc;
                    if (kg > qg) v0 = -1e30f;
                    if (kg + 32 > qg) v1 = -1e30f;
                }
                s0[r] = v0; s1[r] = v1;
            }

            // ---- tree max over 32 + partner exchange ----
            float t8[8];
            #pragma unroll
            for (int z = 0; z < 8; z++)
                t8[z] = fmaxf(fmaxf(s0[2 * z], s0[2 * z + 1]),
                              fmaxf(s1[2 * z], s1[2 * z + 1]));
            float mx = fmaxf(fmaxf(fmaxf(t8[0], t8[1]), fmaxf(t8[2], t8[3])),
                             fmaxf(fmaxf(t8[4], t8[5]), fmaxf(t8[6], t8[7])));
            mx = fmaxf(mx, __shfl_xor(mx, 32, 64));
            bool sk = (mx <= m + 8.0f);             // defer-max (T13)
            float mn = sk ? m : mx;
            float corr = sk ? 1.0f : __expf(m - mn);
            m = mn;

            // ---- exp in place + 4-partial sum ----
            float ts0 = 0.f, ts1 = 0.f, ts2 = 0.f, ts3 = 0.f;
            #pragma unroll
            for (int z = 0; z < 8; z++) {
                s0[z]     = __expf(s0[z]     - mn); ts0 += s0[z];
                s0[z + 8] = __expf(s0[z + 8] - mn); ts1 += s0[z + 8];
                s1[z]     = __expf(s1[z]     - mn); ts2 += s1[z];
                s1[z + 8] = __expf(s1[z + 8] - mn); ts3 += s1[z + 8];
            }
            float ts = (ts0 + ts1) + (ts2 + ts3);
            ts += __shfl_xor(ts, 32, 64);
            lsum = lsum * corr + ts;
            if (!__all(sk)) {                       // rare rescale, scalar temp
                #pragma unroll
                for (int r = 0; r < 16; r++) {
                    float c = __shfl(corr, (r & 3) + 8 * (r >> 2) + 4 * hi, 64);
                    acc[0][r] *= c; acc[1][r] *= c; acc[2][r] *= c; acc[3][r] *= c;
                }
            }

            // ---- pack P -> PV A-fragments, windowed (no arrays) ----
            bf16x8 pf[4];
            #pragma unroll
            for (int g2 = 0; g2 < 2; g2++)
                #pragma unroll
                for (int ksl = 0; ksl < 2; ksl++) {
                    u32 ua0, ua1, ua2, ua3;
                    {
                        float a0 = g2 ? s1[8 * ksl + 0] : s0[8 * ksl + 0];
                        float a1 = g2 ? s1[8 * ksl + 1] : s0[8 * ksl + 1];
                        float a2 = g2 ? s1[8 * ksl + 2] : s0[8 * ksl + 2];
                        float a3 = g2 ? s1[8 * ksl + 3] : s0[8 * ksl + 3];
                        float a4 = g2 ? s1[8 * ksl + 4] : s0[8 * ksl + 4];
                        float a5 = g2 ? s1[8 * ksl + 5] : s0[8 * ksl + 5];
                        float a6 = g2 ? s1[8 * ksl + 6] : s0[8 * ksl + 6];
                        float a7 = g2 ? s1[8 * ksl + 7] : s0[8 * ksl + 7];
                        asm("v_cvt_pk_bf16_f32 %0, %1, %2" : "=v"(ua0) : "v"(a0), "v"(a1));
                        asm("v_cvt_pk_bf16_f32 %0, %1, %2" : "=v"(ua1) : "v"(a2), "v"(a3));
                        asm("v_cvt_pk_bf16_f32 %0, %1, %2" : "=v"(ua2) : "v"(a4), "v"(a5));
                        asm("v_cvt_pk_bf16_f32 %0, %1, %2" : "=v"(ua3) : "v"(a6), "v"(a7));
                    }
                    u32 sa0 = __shfl_xor(ua0, 32, 64), sa1 = __shfl_xor(ua1, 32, 64);
                    u32 sa2 = __shfl_xor(ua2, 32, 64), sa3 = __shfl_xor(ua3, 32, 64);
                    int4 w4 = hi ? make_int4(sa2, sa3, ua2, ua3)
                                 : make_int4(ua0, ua1, sa0, sa1);
                    pf[2 * g2 + ksl] = __builtin_bit_cast(bf16x8, w4);
                }

            // ---- PV: acc[db] += P(32q x 64k) * V(64k x 32d) ----
            __builtin_amdgcn_s_setprio(1);
            #pragma unroll
            for (int db = 0; db < 4; db++) {
                int row = 32 * db + ql;
                #pragma unroll
                for (int ks = 0; ks < 4; ks++) {
                    bf16x8 vf = ld_bf8(VtB + row * 128 + (((2 * ks + hi) ^ (row & 7)) << 4));
                    acc[db] = __builtin_amdgcn_mfma_f32_32x32x16_bf16(pf[ks], vf, acc[db], 0, 0, 0);
                }
            }
            __builtin_amdgcn_s_setprio(0);
        }

        asm volatile("s_waitcnt lgkmcnt(0)" ::: "memory");
        __builtin_amdgcn_sched_barrier(0);
        asm volatile("s_waitcnt vmcnt(0)" ::: "memory");
        __builtin_amdgcn_s_barrier();
    }

    // ---- epilogue: per-row scalar reciprocal, no arrays ----
    #pragma unroll
    for (int r = 0; r < 16; r++) {
        int crow = (r & 3) + 8 * (r >> 2) + 4 * hi;
        float riv = 1.0f / __shfl(lsum, crow, 64);
        #pragma unroll
        for (int db = 0; db < 4; db++)
            Ab[(size_t)(q0w + crow) * DMODEL + h * DHEAD + db * 32 + ql]
                = f2bf(acc[db][r] * riv);
    }
}

extern "C" void kernel_launch(void* const* d_in, const int* in_sizes, int n_in,
                              void* d_out, int out_size, void* d_ws, size_t ws_size,
                              hipStream_t stream) {
    const float* hidden = (const float*)d_in[0];
    const float* cosT   = (const float*)d_in[1];
    const float* sinT   = (const float*)d_in[2];
    // d_in[3] attention_mask: known causal, implemented directly
    const float* Wq = (const float*)d_in[4];
    const float* Wk = (const float*)d_in[5];
    const float* Wv = (const float*)d_in[6];
    const float* Wo = (const float*)d_in[7];
    float* out = (float*)d_out;
    char* ws = (char*)d_ws;

    u16* Xbf   = (u16*)ws;
    u16* WqkvT = (u16*)(ws + (16u << 20));
    u16* VbT   = (u16*)(ws + (16u << 20));          // alias: valid after QKV GEMM
    u16* WoT   = (u16*)(ws + (64u << 20));
    u16* QKVb  = (u16*)(ws + (96u << 20));
    u16* Ab    = Xbf;

    k_cvt<<<dim3((S_LEN * DMODEL / 8) / 256), 256, 0, stream>>>(hidden, Xbf, S_LEN * DMODEL / 8);
    k_transpose_w<<<dim3(4096 / 64, 4096 / 64), 256, 0, stream>>>(Wq, WqkvT, 4096, 4096);
    k_transpose_w<<<dim3(1024 / 64, 4096 / 64), 256, 0, stream>>>(Wk, WqkvT + (size_t)4096 * 4096, 4096, 1024);
    k_transpose_w<<<dim3(1024 / 64, 4096 / 64), 256, 0, stream>>>(Wv, WqkvT + (size_t)5120 * 4096, 4096, 1024);
    k_transpose_w<<<dim3(4096 / 64, 4096 / 64), 256, 0, stream>>>(Wo, WoT, 4096, 4096);

    // fused QKV projection: [2048][4096] x [6144][4096]^T -> [2048][6144]
    k_gemm_bt2<u16><<<dim3(6144 / 128, 2048 / 128), 256, 0, stream>>>(Xbf, WqkvT, QKVb, 2048, 6144, 4096);

    // RoPE on Q (cols 0..4095) and K (cols 4096..5119)
    k_rope<<<(2048 * 32 * 64) / 256, 256, 0, stream>>>(QKVb, cosT, sinT, 32, LDQK);
    k_rope<<<(2048 * 8 * 64) / 256, 256, 0, stream>>>(QKVb + 4096, cosT, sinT, 8, LDQK);

    // V^T (cols 5120..6143 of QKVb) -> VbT [1024][2048]
    k_transpose_bf16<u16><<<dim3(1024 / 32, 2048 / 32), 256, 0, stream>>>(QKVb + 5120, VbT, 2048, 1024, LDQK);

    // attention v4: 512 blocks (t anti-correlated across halves), 64 KB dynamic LDS
    hipFuncSetAttribute((const void*)k_attn3, hipFuncAttributeMaxDynamicSharedMemorySize, 65536);
    k_attn3<<<dim3(512), 256, 65536, stream>>>(QKVb, QKVb + 4096, VbT, Ab);

    // output projection (fp32 out)
    k_gemm_bt2<float><<<dim3(4096 / 128, 2048 / 128), 256, 0, stream>>>(Ab, WoT, out, 2048, 4096, 4096);
}